// Round 1
// baseline (438.866 us; speedup 1.0000x reference)
//
#include <hip/hip_runtime.h>
#include <hip/hip_bf16.h>

// Problem constants (match reference)
#define NNODE_DIN 128
#define NNODE_DOUT 128
#define DEG 48
#define TOPK 32

typedef __bf16 bf16x8 __attribute__((ext_vector_type(8)));
typedef unsigned short ushortx8 __attribute__((ext_vector_type(8)));
typedef float floatx4 __attribute__((ext_vector_type(4)));

__device__ inline unsigned short f2bf(float f) {
    __bf16 h = (__bf16)f;
    return __builtin_bit_cast(unsigned short, h);
}
__device__ inline float bf2f(unsigned short u) {
    unsigned v = ((unsigned)u) << 16;
    return __builtin_bit_cast(float, v);
}
// Raw transcendentals: tolerance is ~1e-2 absmax; ~1e-7 rel error is free speed.
__device__ inline float fast_sqrt(float x) {
    float r; asm("v_sqrt_f32 %0, %1" : "=v"(r) : "v"(x)); return r;
}
__device__ inline float fast_exp(float x) {  // e^x, x <= 0 here (no overflow path)
    float t = x * 1.44269504088896341f;
    float r; asm("v_exp_f32 %0, %1" : "=v"(r) : "v"(t)); return r;
}
__device__ inline float fast_rcp(float x) {
    float r; asm("v_rcp_f32 %0, %1" : "=v"(r) : "v"(x)); return r;
}

// ---------------------------------------------------------------------------
// Kernel 0: pre-swizzle W^T into split-bf16 MFMA B-fragments in k1's load
// order. frag (nt,kt,lane) holds W[k][n], n = nt*16+(lane&15),
// k = kt*32+(lane>>4)*8+e. 2048 frags x 16 B per array (hi, lo).
// ---------------------------------------------------------------------------
__global__ __launch_bounds__(256) void k0_wprep(
    const float* __restrict__ w, unsigned short* __restrict__ wth,
    unsigned short* __restrict__ wtl) {
    int tid = blockIdx.x * 256 + threadIdx.x;  // 0..2047
    int lane = tid & 63;
    int kt = (tid >> 6) & 3;
    int nt = tid >> 8;
    int m = lane & 15, q = lane >> 4;
    int nn = nt * 16 + m;
    int k0 = kt * 32 + q * 8;
    ushortx8 uh, ul;
#pragma unroll
    for (int e = 0; e < 8; ++e) {
        float v = w[(size_t)(k0 + e) * 128 + nn];
        unsigned short h = f2bf(v);
        uh[e] = h;
        ul[e] = f2bf(v - bf2f(h));
    }
    *(ushortx8*)(wth + tid * 8) = uh;
    *(ushortx8*)(wtl + tid * 8) = ul;
}

// ---------------------------------------------------------------------------
// Kernel 1: x = feat @ W via split-bf16 MFMA. RESTRUCTURED vs prev round:
// the old fully-unrolled 64-load/96-MFMA body let the scheduler hoist up to
// 256 VGPRs of B-fragments -> suspected scratch spills (k1 measured ~7x over
// its memory floor). Now: nt-loop with per-nt accumulator (4 regs live),
// immediate LDS write, unroll 2 for pipelining, explicit occupancy bound.
// ---------------------------------------------------------------------------
__global__ __launch_bounds__(64, 4) void k1_mfma(
    const float* __restrict__ feat, const unsigned short* __restrict__ wth,
    const unsigned short* __restrict__ wtl, unsigned short* __restrict__ xh,
    unsigned short* __restrict__ xl, int n) {
    __shared__ float s_x[16 * 132];
    int l = threadIdx.x;
    int m = l & 15, q = l >> 4;
    int r0 = blockIdx.x * 16;

    // A-fragments: feat rows r0+m, split into hi/lo bf16
    bf16x8 ah[4], al[4];
#pragma unroll
    for (int kt = 0; kt < 4; ++kt) {
        float vv[8];
        if (r0 + m < n) {
            const float* src = feat + (size_t)(r0 + m) * 128 + kt * 32 + q * 8;
            float4 v0 = *(const float4*)src;
            float4 v1 = *(const float4*)(src + 4);
            vv[0] = v0.x; vv[1] = v0.y; vv[2] = v0.z; vv[3] = v0.w;
            vv[4] = v1.x; vv[5] = v1.y; vv[6] = v1.z; vv[7] = v1.w;
        } else {
#pragma unroll
            for (int e = 0; e < 8; ++e) vv[e] = 0.0f;
        }
        ushortx8 uh, ul;
#pragma unroll
        for (int e = 0; e < 8; ++e) {
            unsigned short h = f2bf(vv[e]);
            uh[e] = h;
            ul[e] = f2bf(vv[e] - bf2f(h));
        }
        ah[kt] = __builtin_bit_cast(bf16x8, uh);
        al[kt] = __builtin_bit_cast(bf16x8, ul);
    }

#pragma unroll 2
    for (int nt = 0; nt < 8; ++nt) {
        floatx4 a = (floatx4){0.f, 0.f, 0.f, 0.f};
#pragma unroll
        for (int kt = 0; kt < 4; ++kt) {
            int fo = ((nt * 4 + kt) * 64 + l) * 8;
            bf16x8 bh = *(const bf16x8*)(wth + fo);
            bf16x8 bl = *(const bf16x8*)(wtl + fo);
            a = __builtin_amdgcn_mfma_f32_16x16x32_bf16(ah[kt], bh, a, 0, 0, 0);
            a = __builtin_amdgcn_mfma_f32_16x16x32_bf16(ah[kt], bl, a, 0, 0, 0);
            a = __builtin_amdgcn_mfma_f32_16x16x32_bf16(al[kt], bh, a, 0, 0, 0);
        }
        // D layout: a[r] = x[r0 + q*4 + r][nt*16 + m] -> stage transpose in LDS
#pragma unroll
        for (int r = 0; r < 4; ++r)
            s_x[(q * 4 + r) * 132 + nt * 16 + m] = a[r];
    }
    __syncthreads();

#pragma unroll
    for (int rr = 0; rr < 2; ++rr) {
        int row = rr * 8 + (l >> 3);
        int c0 = (l & 7) * 16;
        if (r0 + row < n) {
            float vv[16];
#pragma unroll
            for (int j = 0; j < 4; ++j) {
                float4 v = *(const float4*)&s_x[row * 132 + c0 + j * 4];
                vv[j * 4 + 0] = v.x; vv[j * 4 + 1] = v.y;
                vv[j * 4 + 2] = v.z; vv[j * 4 + 3] = v.w;
            }
            unsigned uh[8], ul[8];
#pragma unroll
            for (int p = 0; p < 8; ++p) {
                unsigned short h0 = f2bf(vv[2 * p]);
                unsigned short h1 = f2bf(vv[2 * p + 1]);
                unsigned short l0 = f2bf(vv[2 * p] - bf2f(h0));
                unsigned short l1 = f2bf(vv[2 * p + 1] - bf2f(h1));
                uh[p] = (unsigned)h0 | ((unsigned)h1 << 16);
                ul[p] = (unsigned)l0 | ((unsigned)l1 << 16);
            }
            size_t off = (size_t)(r0 + row) * 128 + c0;
            *(uint4*)(xh + off) = make_uint4(uh[0], uh[1], uh[2], uh[3]);
            *(uint4*)(xh + off + 8) = make_uint4(uh[4], uh[5], uh[6], uh[7]);
            *(uint4*)(xl + off) = make_uint4(ul[0], ul[1], ul[2], ul[3]);
            *(uint4*)(xl + off + 8) = make_uint4(ul[4], ul[5], ul[6], ul[7]);
        }
    }
}

// ---------------------------------------------------------------------------
// Kernel 2: one wave per node, 4 nodes per 256-thread block (per-wave LDS
// slices). RESTRUCTURED vs prev round: the 8.3 KB s_red epilogue buffer is
// replaced by a __shfl_xor (DPP) 16-lane reduction + coalesced float2 store,
// cutting LDS 9728 -> ~4.3 KB so occupancy is no longer LDS/workgroup-limited
// (was 41%, latency-bound with VALU 54% / MFMA 11% / HBM 30%).
// ---------------------------------------------------------------------------
__global__ __launch_bounds__(256, 6) void k2_conv(
    const float* __restrict__ ew, const int* __restrict__ nbr,
    const float* __restrict__ bias, const unsigned short* __restrict__ xh,
    const unsigned short* __restrict__ xl, float* __restrict__ outp, int n) {
    __shared__ float s_w[4][52];
    __shared__ int s_nb[4][52];
    __shared__ float s_tw[4][32];
    __shared__ int s_id[4][32];
    __shared__ float s_diag[4][32];
    __shared__ float s_dist[4][32];
    __shared__ float s_omega[4][32];

    int wv = threadIdx.x >> 6;
    int l = threadIdx.x & 63;
    int i = blockIdx.x * 4 + wv;
    if (i >= n) i = n - 1;  // duplicate compute of last node (benign same-value write)

    // A: candidates = 48 neighbors + self loop (weight 1.0)
    if (l < DEG + 1) {
        bool self = (l == DEG);
        s_w[wv][l] = self ? 1.0f : ew[(size_t)i * DEG + l];
        s_nb[wv][l] = self ? i : nbr[(size_t)i * DEG + l];
    }
    __syncthreads();

    // B: rank-based top-k (exact jax.lax.top_k tie semantics); rank == slot
    if (l < DEG + 1) {
        float wj = s_w[wv][l];
        int rank = 0;
#pragma unroll
        for (int t2 = 0; t2 < DEG + 1; ++t2) {
            float wt = s_w[wv][t2];
            rank += (wt > wj) || ((wt == wj) && (t2 < l)) ? 1 : 0;
        }
        if (rank < TOPK) {
            s_tw[wv][rank] = wj;
            s_id[wv][rank] = s_nb[wv][l];
        }
    }
    __syncthreads();

    // C: gather fragment pointers; compiler is free to rematerialize the
    // loads in phase G (it already chose to at VGPR=52 last round).
    int m = l & 15;
    int q = l >> 4;
    int row0 = s_id[wv][m];
    int row1 = s_id[wv][16 + m];
    const __bf16* gh0 = (const __bf16*)(xh + (size_t)row0 * 128) + q * 8;
    const __bf16* gh1 = (const __bf16*)(xh + (size_t)row1 * 128) + q * 8;
    const __bf16* gl0 = (const __bf16*)(xl + (size_t)row0 * 128) + q * 8;
    const __bf16* gl1 = (const __bf16*)(xl + (size_t)row1 * 128) + q * 8;

    bf16x8 H0[4], H1[4], L0[4], L1[4];
#pragma unroll
    for (int kt = 0; kt < 4; ++kt) {
        H0[kt] = *(const bf16x8*)(gh0 + kt * 32);
        H1[kt] = *(const bf16x8*)(gh1 + kt * 32);
        L0[kt] = *(const bf16x8*)(gl0 + kt * 32);
        L1[kt] = *(const bf16x8*)(gl1 + kt * 32);
    }

    // D: Gram = X*X^T with X ~= H + L: G = HH^T + HL^T + LH^T
    floatx4 acc[2][2];
#pragma unroll
    for (int a = 0; a < 2; ++a)
#pragma unroll
        for (int b = 0; b < 2; ++b) acc[a][b] = (floatx4){0.f, 0.f, 0.f, 0.f};

#pragma unroll
    for (int kt = 0; kt < 4; ++kt) {
        bf16x8 h0 = H0[kt], h1 = H1[kt], l0 = L0[kt], l1 = L1[kt];
        acc[0][0] = __builtin_amdgcn_mfma_f32_16x16x32_bf16(h0, h0, acc[0][0], 0, 0, 0);
        acc[0][0] = __builtin_amdgcn_mfma_f32_16x16x32_bf16(h0, l0, acc[0][0], 0, 0, 0);
        acc[0][0] = __builtin_amdgcn_mfma_f32_16x16x32_bf16(l0, h0, acc[0][0], 0, 0, 0);
        acc[0][1] = __builtin_amdgcn_mfma_f32_16x16x32_bf16(h0, h1, acc[0][1], 0, 0, 0);
        acc[0][1] = __builtin_amdgcn_mfma_f32_16x16x32_bf16(h0, l1, acc[0][1], 0, 0, 0);
        acc[0][1] = __builtin_amdgcn_mfma_f32_16x16x32_bf16(l0, h1, acc[0][1], 0, 0, 0);
        acc[1][0] = __builtin_amdgcn_mfma_f32_16x16x32_bf16(h1, h0, acc[1][0], 0, 0, 0);
        acc[1][0] = __builtin_amdgcn_mfma_f32_16x16x32_bf16(h1, l0, acc[1][0], 0, 0, 0);
        acc[1][0] = __builtin_amdgcn_mfma_f32_16x16x32_bf16(l1, h0, acc[1][0], 0, 0, 0);
        acc[1][1] = __builtin_amdgcn_mfma_f32_16x16x32_bf16(h1, h1, acc[1][1], 0, 0, 0);
        acc[1][1] = __builtin_amdgcn_mfma_f32_16x16x32_bf16(h1, l1, acc[1][1], 0, 0, 0);
        acc[1][1] = __builtin_amdgcn_mfma_f32_16x16x32_bf16(l1, h1, acc[1][1], 0, 0, 0);
    }

    // D2: extract diagonal (sq) from Gram so that d2_aa == 0 exactly
    if (q == (m >> 2)) {
        int rd = m & 3;
        s_diag[wv][m] = acc[0][0][rd];
        s_diag[wv][16 + m] = acc[1][1][rd];
    }
    __syncthreads();

    // E: dist[a] = sum_b tw[b] * sqrt(d2 masked by d2>0)
    {
        float db0 = s_diag[wv][m];
        float db1 = s_diag[wv][16 + m];
        float tw0 = s_tw[wv][m];
        float tw1 = s_tw[wv][16 + m];
#pragma unroll
        for (int ma = 0; ma < 2; ++ma) {
#pragma unroll
            for (int r = 0; r < 4; ++r) {
                int a = ma * 16 + q * 4 + r;
                float da = s_diag[wv][a];
                float g0 = acc[ma][0][r];
                float g1 = acc[ma][1][r];
                float d20 = da + db0 - 2.0f * g0;
                float d21 = da + db1 - 2.0f * g1;
                float t0 = (d20 > 0.0f) ? fast_sqrt(d20) : 0.0f;
                float t1 = (d21 > 0.0f) ? fast_sqrt(d21) : 0.0f;
                float v = tw0 * t0 + tw1 * t1;
                v += __shfl_xor(v, 1);
                v += __shfl_xor(v, 2);
                v += __shfl_xor(v, 4);
                v += __shfl_xor(v, 8);
                if (m == 0) s_dist[wv][a] = v;
            }
        }
    }
    __syncthreads();

    // F: omega = exp(-dist - max(-dist)) * tw, normalized
    {
        int k32 = l & 31;
        float s = s_dist[wv][k32];
        float mn = s;
        mn = fminf(mn, __shfl_xor(mn, 1));
        mn = fminf(mn, __shfl_xor(mn, 2));
        mn = fminf(mn, __shfl_xor(mn, 4));
        mn = fminf(mn, __shfl_xor(mn, 8));
        mn = fminf(mn, __shfl_xor(mn, 16));
        float e = fast_exp(mn - s) * s_tw[wv][k32];
        float sum = e;
        sum += __shfl_xor(sum, 1);
        sum += __shfl_xor(sum, 2);
        sum += __shfl_xor(sum, 4);
        sum += __shfl_xor(sum, 8);
        sum += __shfl_xor(sum, 16);
        float om = e * fast_rcp(sum);
        if (l < 32) s_omega[wv][l] = om;
    }
    __syncthreads();

    // G: aggregate via register partials + __shfl_xor reduction over the 16
    // m-lanes (DPP-expressible masks 1/2/4/8). No LDS buffer, no extra
    // barriers. Then one coalesced float2 store per lane:
    // lane (m,q) owns d = (m>>2)*32 + q*8 + (m&3)*2  (all 64 d's distinct).
    {
        float w0 = s_omega[wv][m];
        float w1 = s_omega[wv][16 + m];
        float o0 = 0.f, o1 = 0.f;
#pragma unroll
        for (int kt = 0; kt < 4; ++kt) {
            float p[8];
#pragma unroll
            for (int e = 0; e < 8; ++e) {
                float x0 = (float)H0[kt][e] + (float)L0[kt][e];
                float x1 = (float)H1[kt][e] + (float)L1[kt][e];
                p[e] = w0 * x0 + w1 * x1;
            }
#pragma unroll
            for (int e = 0; e < 8; ++e) {
                p[e] += __shfl_xor(p[e], 1);
                p[e] += __shfl_xor(p[e], 2);
                p[e] += __shfl_xor(p[e], 4);
                p[e] += __shfl_xor(p[e], 8);
            }
            // compile-time select of this lane's pair (kt == m>>2, j == m&3)
#pragma unroll
            for (int j = 0; j < 4; ++j) {
                if (m == kt * 4 + j) {
                    o0 = p[2 * j];
                    o1 = p[2 * j + 1];
                }
            }
        }
        int d = (m >> 2) * 32 + q * 8 + (m & 3) * 2;
        float2 bb = *(const float2*)(bias + d);
        *(float2*)(outp + (size_t)i * 128 + d) = make_float2(o0 + bb.x, o1 + bb.y);
    }
}

extern "C" void kernel_launch(void* const* d_in, const int* in_sizes, int n_in,
                              void* d_out, int out_size, void* d_ws, size_t ws_size,
                              hipStream_t stream) {
    const float* feat = (const float*)d_in[0];
    const float* ew = (const float*)d_in[1];
    const float* weight = (const float*)d_in[2];
    const float* bias = (const float*)d_in[3];
    const int* nbr = (const int*)d_in[4];
    float* outp = (float*)d_out;
    int n = in_sizes[0] / NNODE_DIN;  // 50000

    unsigned short* xh = (unsigned short*)d_ws;            // n x 128 bf16
    unsigned short* xl = xh + (size_t)n * NNODE_DOUT;      // n x 128 bf16
    unsigned short* wth = xl + (size_t)n * NNODE_DOUT;     // 2048 frags x 16B
    unsigned short* wtl = wth + 2048 * 8;

    hipLaunchKernelGGL(k0_wprep, dim3(8), dim3(256), 0, stream, weight, wth, wtl);
    int grid1 = (n + 15) / 16;
    hipLaunchKernelGGL(k1_mfma, dim3(grid1), dim3(64), 0, stream, feat, wth, wtl, xh, xl, n);
    int grid2 = (n + 3) / 4;
    hipLaunchKernelGGL(k2_conv, dim3(grid2), dim3(256), 0, stream, ew, nbr, bias, xh, xl, outp, n);
}

// Round 3
// 415.956 us; speedup vs baseline: 1.0551x; 1.0551x over previous
//
#include <hip/hip_runtime.h>
#include <hip/hip_bf16.h>

// Problem constants (match reference)
#define NNODE_DIN 128
#define NNODE_DOUT 128
#define DEG 48
#define TOPK 32

typedef __bf16 bf16x8 __attribute__((ext_vector_type(8)));
typedef unsigned short ushortx8 __attribute__((ext_vector_type(8)));
typedef float floatx4 __attribute__((ext_vector_type(4)));

__device__ inline unsigned short f2bf(float f) {
    __bf16 h = (__bf16)f;
    return __builtin_bit_cast(unsigned short, h);
}
__device__ inline float bf2f(unsigned short u) {
    unsigned v = ((unsigned)u) << 16;
    return __builtin_bit_cast(float, v);
}
// Raw transcendentals: tolerance is loose; ~1e-7 rel error is free speed.
// (Proven safe in round 1.)
__device__ inline float fast_sqrt(float x) {
    float r; asm("v_sqrt_f32 %0, %1" : "=v"(r) : "v"(x)); return r;
}
__device__ inline float fast_exp(float x) {  // e^x, x <= 0 here (no overflow path)
    float t = x * 1.44269504088896341f;
    float r; asm("v_exp_f32 %0, %1" : "=v"(r) : "v"(t)); return r;
}
__device__ inline float fast_rcp(float x) {
    float r; asm("v_rcp_f32 %0, %1" : "=v"(r) : "v"(x)); return r;
}

// ---------------------------------------------------------------------------
// Kernel 0: pre-swizzle W^T into split-bf16 MFMA B-fragments in k1's load
// order. frag (nt,kt,lane) holds W[k][n], n = nt*16+(lane&15),
// k = kt*32+(lane>>4)*8+e. 2048 frags x 16 B per array (hi, lo).
// ---------------------------------------------------------------------------
__global__ __launch_bounds__(256) void k0_wprep(
    const float* __restrict__ w, unsigned short* __restrict__ wth,
    unsigned short* __restrict__ wtl) {
    int tid = blockIdx.x * 256 + threadIdx.x;  // 0..2047
    int lane = tid & 63;
    int kt = (tid >> 6) & 3;
    int nt = tid >> 8;
    int m = lane & 15, q = lane >> 4;
    int nn = nt * 16 + m;
    int k0 = kt * 32 + q * 8;
    ushortx8 uh, ul;
#pragma unroll
    for (int e = 0; e < 8; ++e) {
        float v = w[(size_t)(k0 + e) * 128 + nn];
        unsigned short h = f2bf(v);
        uh[e] = h;
        ul[e] = f2bf(v - bf2f(h));
    }
    *(ushortx8*)(wth + tid * 8) = uh;
    *(ushortx8*)(wtl + tid * 8) = ul;
}

// ---------------------------------------------------------------------------
// Kernel 1: x = feat @ W via split-bf16 MFMA (held constant).
// ---------------------------------------------------------------------------
__global__ __launch_bounds__(64, 4) void k1_mfma(
    const float* __restrict__ feat, const unsigned short* __restrict__ wth,
    const unsigned short* __restrict__ wtl, unsigned short* __restrict__ xh,
    unsigned short* __restrict__ xl, int n) {
    __shared__ float s_x[16 * 132];
    int l = threadIdx.x;
    int m = l & 15, q = l >> 4;
    int r0 = blockIdx.x * 16;

    bf16x8 ah[4], al[4];
#pragma unroll
    for (int kt = 0; kt < 4; ++kt) {
        float vv[8];
        if (r0 + m < n) {
            const float* src = feat + (size_t)(r0 + m) * 128 + kt * 32 + q * 8;
            float4 v0 = *(const float4*)src;
            float4 v1 = *(const float4*)(src + 4);
            vv[0] = v0.x; vv[1] = v0.y; vv[2] = v0.z; vv[3] = v0.w;
            vv[4] = v1.x; vv[5] = v1.y; vv[6] = v1.z; vv[7] = v1.w;
        } else {
#pragma unroll
            for (int e = 0; e < 8; ++e) vv[e] = 0.0f;
        }
        ushortx8 uh, ul;
#pragma unroll
        for (int e = 0; e < 8; ++e) {
            unsigned short h = f2bf(vv[e]);
            uh[e] = h;
            ul[e] = f2bf(vv[e] - bf2f(h));
        }
        ah[kt] = __builtin_bit_cast(bf16x8, uh);
        al[kt] = __builtin_bit_cast(bf16x8, ul);
    }

#pragma unroll 2
    for (int nt = 0; nt < 8; ++nt) {
        floatx4 a = (floatx4){0.f, 0.f, 0.f, 0.f};
#pragma unroll
        for (int kt = 0; kt < 4; ++kt) {
            int fo = ((nt * 4 + kt) * 64 + l) * 8;
            bf16x8 bh = *(const bf16x8*)(wth + fo);
            bf16x8 bl = *(const bf16x8*)(wtl + fo);
            a = __builtin_amdgcn_mfma_f32_16x16x32_bf16(ah[kt], bh, a, 0, 0, 0);
            a = __builtin_amdgcn_mfma_f32_16x16x32_bf16(ah[kt], bl, a, 0, 0, 0);
            a = __builtin_amdgcn_mfma_f32_16x16x32_bf16(al[kt], bh, a, 0, 0, 0);
        }
#pragma unroll
        for (int r = 0; r < 4; ++r)
            s_x[(q * 4 + r) * 132 + nt * 16 + m] = a[r];
    }
    __syncthreads();

#pragma unroll
    for (int rr = 0; rr < 2; ++rr) {
        int row = rr * 8 + (l >> 3);
        int c0 = (l & 7) * 16;
        if (r0 + row < n) {
            float vv[16];
#pragma unroll
            for (int j = 0; j < 4; ++j) {
                float4 v = *(const float4*)&s_x[row * 132 + c0 + j * 4];
                vv[j * 4 + 0] = v.x; vv[j * 4 + 1] = v.y;
                vv[j * 4 + 2] = v.z; vv[j * 4 + 3] = v.w;
            }
            unsigned uh[8], ul[8];
#pragma unroll
            for (int p = 0; p < 8; ++p) {
                unsigned short h0 = f2bf(vv[2 * p]);
                unsigned short h1 = f2bf(vv[2 * p + 1]);
                unsigned short l0 = f2bf(vv[2 * p] - bf2f(h0));
                unsigned short l1 = f2bf(vv[2 * p + 1] - bf2f(h1));
                uh[p] = (unsigned)h0 | ((unsigned)h1 << 16);
                ul[p] = (unsigned)l0 | ((unsigned)l1 << 16);
            }
            size_t off = (size_t)(r0 + row) * 128 + c0;
            *(uint4*)(xh + off) = make_uint4(uh[0], uh[1], uh[2], uh[3]);
            *(uint4*)(xh + off + 8) = make_uint4(uh[4], uh[5], uh[6], uh[7]);
            *(uint4*)(xl + off) = make_uint4(ul[0], ul[1], ul[2], ul[3]);
            *(uint4*)(xl + off + 8) = make_uint4(ul[4], ul[5], ul[6], ul[7]);
        }
    }
}

// ---------------------------------------------------------------------------
// Kernel 2: one wave per node, 4 nodes per 256-thread block, __syncthreads
// barriers (PROVEN in round 1 — the round-2 wave-local lgkmcnt fence was the
// only untested ingredient and the bench device-aborted; reverted).
// Round-0 epilogue body (52 VGPR, no scratch) + s_red shrunk 16x130 -> 4x130
// via per-kt shfl_xor(8),(4) pre-reduction with immediate LDS store.
// LDS ~12.5 KB/block; launch_bounds(256,6) caps VGPR at ~85 (need ~55).
// ---------------------------------------------------------------------------
__global__ __launch_bounds__(256, 6) void k2_conv(
    const float* __restrict__ ew, const int* __restrict__ nbr,
    const float* __restrict__ bias, const unsigned short* __restrict__ xh,
    const unsigned short* __restrict__ xl, float* __restrict__ outp, int n) {
    __shared__ float s_w[4][52];
    __shared__ int s_nb[4][52];
    __shared__ float s_tw[4][32];
    __shared__ int s_id[4][32];
    __shared__ float s_diag[4][32];
    __shared__ float s_dist[4][32];
    __shared__ float s_omega[4][32];
    __shared__ float s_red[4][4 * 130];  // 4 m-classes x 128 cols (+pad)

    int wv = threadIdx.x >> 6;
    int l = threadIdx.x & 63;
    int i = blockIdx.x * 4 + wv;
    if (i >= n) i = n - 1;  // duplicate compute of last node (benign same-value write)

    // A: candidates = 48 neighbors + self loop (weight 1.0)
    if (l < DEG + 1) {
        bool self = (l == DEG);
        s_w[wv][l] = self ? 1.0f : ew[(size_t)i * DEG + l];
        s_nb[wv][l] = self ? i : nbr[(size_t)i * DEG + l];
    }
    __syncthreads();

    // B: rank-based top-k (exact jax.lax.top_k tie semantics); rank == slot
    if (l < DEG + 1) {
        float wj = s_w[wv][l];
        int rank = 0;
#pragma unroll
        for (int t2 = 0; t2 < DEG + 1; ++t2) {
            float wt = s_w[wv][t2];
            rank += (wt > wj) || ((wt == wj) && (t2 < l)) ? 1 : 0;
        }
        if (rank < TOPK) {
            s_tw[wv][rank] = wj;
            s_id[wv][rank] = s_nb[wv][l];
        }
    }
    __syncthreads();

    // C: gather fragment pointers; compiler may rematerialize loads in G
    // (it chose exactly that at VGPR=52 in the known-good round).
    int m = l & 15;
    int q = l >> 4;
    int row0 = s_id[wv][m];
    int row1 = s_id[wv][16 + m];
    const __bf16* gh0 = (const __bf16*)(xh + (size_t)row0 * 128) + q * 8;
    const __bf16* gh1 = (const __bf16*)(xh + (size_t)row1 * 128) + q * 8;
    const __bf16* gl0 = (const __bf16*)(xl + (size_t)row0 * 128) + q * 8;
    const __bf16* gl1 = (const __bf16*)(xl + (size_t)row1 * 128) + q * 8;

    bf16x8 H0[4], H1[4], L0[4], L1[4];
#pragma unroll
    for (int kt = 0; kt < 4; ++kt) {
        H0[kt] = *(const bf16x8*)(gh0 + kt * 32);
        H1[kt] = *(const bf16x8*)(gh1 + kt * 32);
        L0[kt] = *(const bf16x8*)(gl0 + kt * 32);
        L1[kt] = *(const bf16x8*)(gl1 + kt * 32);
    }

    // D: Gram = X*X^T with X ~= H + L: G = HH^T + HL^T + LH^T
    floatx4 acc[2][2];
#pragma unroll
    for (int a = 0; a < 2; ++a)
#pragma unroll
        for (int b = 0; b < 2; ++b) acc[a][b] = (floatx4){0.f, 0.f, 0.f, 0.f};

#pragma unroll
    for (int kt = 0; kt < 4; ++kt) {
        bf16x8 h0 = H0[kt], h1 = H1[kt], l0 = L0[kt], l1 = L1[kt];
        acc[0][0] = __builtin_amdgcn_mfma_f32_16x16x32_bf16(h0, h0, acc[0][0], 0, 0, 0);
        acc[0][0] = __builtin_amdgcn_mfma_f32_16x16x32_bf16(h0, l0, acc[0][0], 0, 0, 0);
        acc[0][0] = __builtin_amdgcn_mfma_f32_16x16x32_bf16(l0, h0, acc[0][0], 0, 0, 0);
        acc[0][1] = __builtin_amdgcn_mfma_f32_16x16x32_bf16(h0, h1, acc[0][1], 0, 0, 0);
        acc[0][1] = __builtin_amdgcn_mfma_f32_16x16x32_bf16(h0, l1, acc[0][1], 0, 0, 0);
        acc[0][1] = __builtin_amdgcn_mfma_f32_16x16x32_bf16(l0, h1, acc[0][1], 0, 0, 0);
        acc[1][0] = __builtin_amdgcn_mfma_f32_16x16x32_bf16(h1, h0, acc[1][0], 0, 0, 0);
        acc[1][0] = __builtin_amdgcn_mfma_f32_16x16x32_bf16(h1, l0, acc[1][0], 0, 0, 0);
        acc[1][0] = __builtin_amdgcn_mfma_f32_16x16x32_bf16(l1, h0, acc[1][0], 0, 0, 0);
        acc[1][1] = __builtin_amdgcn_mfma_f32_16x16x32_bf16(h1, h1, acc[1][1], 0, 0, 0);
        acc[1][1] = __builtin_amdgcn_mfma_f32_16x16x32_bf16(h1, l1, acc[1][1], 0, 0, 0);
        acc[1][1] = __builtin_amdgcn_mfma_f32_16x16x32_bf16(l1, h1, acc[1][1], 0, 0, 0);
    }

    // D2: extract diagonal (sq) from Gram so that d2_aa == 0 exactly
    if (q == (m >> 2)) {
        int rd = m & 3;
        s_diag[wv][m] = acc[0][0][rd];
        s_diag[wv][16 + m] = acc[1][1][rd];
    }
    __syncthreads();

    // E: dist[a] = sum_b tw[b] * sqrt(d2 masked by d2>0)
    {
        float db0 = s_diag[wv][m];
        float db1 = s_diag[wv][16 + m];
        float tw0 = s_tw[wv][m];
        float tw1 = s_tw[wv][16 + m];
#pragma unroll
        for (int ma = 0; ma < 2; ++ma) {
#pragma unroll
            for (int r = 0; r < 4; ++r) {
                int a = ma * 16 + q * 4 + r;
                float da = s_diag[wv][a];
                float g0 = acc[ma][0][r];
                float g1 = acc[ma][1][r];
                float d20 = da + db0 - 2.0f * g0;
                float d21 = da + db1 - 2.0f * g1;
                float t0 = (d20 > 0.0f) ? fast_sqrt(d20) : 0.0f;
                float t1 = (d21 > 0.0f) ? fast_sqrt(d21) : 0.0f;
                float v = tw0 * t0 + tw1 * t1;
                v += __shfl_xor(v, 1);
                v += __shfl_xor(v, 2);
                v += __shfl_xor(v, 4);
                v += __shfl_xor(v, 8);
                if (m == 0) s_dist[wv][a] = v;
            }
        }
    }
    __syncthreads();

    // F: omega = exp(-dist - max(-dist)) * tw, normalized
    {
        int k32 = l & 31;
        float s = s_dist[wv][k32];
        float mn = s;
        mn = fminf(mn, __shfl_xor(mn, 1));
        mn = fminf(mn, __shfl_xor(mn, 2));
        mn = fminf(mn, __shfl_xor(mn, 4));
        mn = fminf(mn, __shfl_xor(mn, 8));
        mn = fminf(mn, __shfl_xor(mn, 16));
        float e = fast_exp(mn - s) * s_tw[wv][k32];
        float sum = e;
        sum += __shfl_xor(sum, 1);
        sum += __shfl_xor(sum, 2);
        sum += __shfl_xor(sum, 4);
        sum += __shfl_xor(sum, 8);
        sum += __shfl_xor(sum, 16);
        float om = e * fast_rcp(sum);
        if (l < 32) s_omega[wv][l] = om;
    }
    __syncthreads();

    // G: register partials; pre-reduce over m via shfl_xor(8),(4) -> only 4
    // m-classes hit LDS (s_red 4x130). Immediate per-kt LDS store keeps live
    // ranges short (round 1's spill kept p[] + selects live across kt).
    {
        float w0 = s_omega[wv][m];
        float w1 = s_omega[wv][16 + m];
#pragma unroll
        for (int kt = 0; kt < 4; ++kt) {
            float p[8];
#pragma unroll
            for (int e = 0; e < 8; ++e) {
                float x0 = (float)H0[kt][e] + (float)L0[kt][e];
                float x1 = (float)H1[kt][e] + (float)L1[kt][e];
                p[e] = w0 * x0 + w1 * x1;
            }
#pragma unroll
            for (int e = 0; e < 8; ++e) {
                p[e] += __shfl_xor(p[e], 8);
                p[e] += __shfl_xor(p[e], 4);
            }
            if (m < 4) {  // lane (q, m) now holds sum over {m, m+4, m+8, m+12}
                float* dst = &s_red[wv][m * 130 + kt * 32 + q * 8];
                *(float4*)dst = make_float4(p[0], p[1], p[2], p[3]);
                *(float4*)(dst + 4) = make_float4(p[4], p[5], p[6], p[7]);
            }
        }
    }
    __syncthreads();

    // Final: each lane sums the 4 m-class rows for its 2 columns + bias.
    {
        int d0 = 2 * l;
        float2 bb = *(const float2*)(bias + d0);
        float o0 = bb.x, o1 = bb.y;
#pragma unroll
        for (int r = 0; r < 4; ++r) {
            float2 pr = *(const float2*)&s_red[wv][r * 130 + d0];
            o0 += pr.x;
            o1 += pr.y;
        }
        *(float2*)(outp + (size_t)i * 128 + d0) = make_float2(o0, o1);
    }
}

extern "C" void kernel_launch(void* const* d_in, const int* in_sizes, int n_in,
                              void* d_out, int out_size, void* d_ws, size_t ws_size,
                              hipStream_t stream) {
    const float* feat = (const float*)d_in[0];
    const float* ew = (const float*)d_in[1];
    const float* weight = (const float*)d_in[2];
    const float* bias = (const float*)d_in[3];
    const int* nbr = (const int*)d_in[4];
    float* outp = (float*)d_out;
    int n = in_sizes[0] / NNODE_DIN;  // 50000

    unsigned short* xh = (unsigned short*)d_ws;            // n x 128 bf16
    unsigned short* xl = xh + (size_t)n * NNODE_DOUT;      // n x 128 bf16
    unsigned short* wth = xl + (size_t)n * NNODE_DOUT;     // 2048 frags x 16B
    unsigned short* wtl = wth + 2048 * 8;

    hipLaunchKernelGGL(k0_wprep, dim3(8), dim3(256), 0, stream, weight, wth, wtl);
    int grid1 = (n + 15) / 16;
    hipLaunchKernelGGL(k1_mfma, dim3(grid1), dim3(64), 0, stream, feat, wth, wtl, xh, xl, n);
    int grid2 = (n + 3) / 4;
    hipLaunchKernelGGL(k2_conv, dim3(grid2), dim3(256), 0, stream, ew, nbr, bias, xh, xl, outp, n);
}

// Round 4
// 239.211 us; speedup vs baseline: 1.8346x; 1.7389x over previous
//
#include <hip/hip_runtime.h>
#include <hip/hip_bf16.h>

// Problem constants (match reference)
#define NNODE_DIN 128
#define NNODE_DOUT 128
#define DEG 48
#define TOPK 32

typedef __bf16 bf16x8 __attribute__((ext_vector_type(8)));
typedef unsigned short ushortx8 __attribute__((ext_vector_type(8)));
typedef float floatx4 __attribute__((ext_vector_type(4)));

__device__ inline unsigned short f2bf(float f) {
    __bf16 h = (__bf16)f;
    return __builtin_bit_cast(unsigned short, h);
}
__device__ inline float bf2f(unsigned short u) {
    unsigned v = ((unsigned)u) << 16;
    return __builtin_bit_cast(float, v);
}
// Raw transcendentals: proven correct in rounds 1 & 3 (absmax unchanged).
__device__ inline float fast_sqrt(float x) {
    float r; asm("v_sqrt_f32 %0, %1" : "=v"(r) : "v"(x)); return r;
}
__device__ inline float fast_exp(float x) {  // e^x, x <= 0 here (no overflow path)
    float t = x * 1.44269504088896341f;
    float r; asm("v_exp_f32 %0, %1" : "=v"(r) : "v"(t)); return r;
}
__device__ inline float fast_rcp(float x) {
    float r; asm("v_rcp_f32 %0, %1" : "=v"(r) : "v"(x)); return r;
}

// ---------------------------------------------------------------------------
// Kernel 0: pre-swizzle W^T into split-bf16 MFMA B-fragments in k1's load
// order. frag (nt,kt,lane) holds W[k][n], n = nt*16+(lane&15),
// k = kt*32+(lane>>4)*8+e. 2048 frags x 16 B per array (hi, lo).
// ---------------------------------------------------------------------------
__global__ __launch_bounds__(256) void k0_wprep(
    const float* __restrict__ w, unsigned short* __restrict__ wth,
    unsigned short* __restrict__ wtl) {
    int tid = blockIdx.x * 256 + threadIdx.x;  // 0..2047
    int lane = tid & 63;
    int kt = (tid >> 6) & 3;
    int nt = tid >> 8;
    int m = lane & 15, q = lane >> 4;
    int nn = nt * 16 + m;
    int k0 = kt * 32 + q * 8;
    ushortx8 uh, ul;
#pragma unroll
    for (int e = 0; e < 8; ++e) {
        float v = w[(size_t)(k0 + e) * 128 + nn];
        unsigned short h = f2bf(v);
        uh[e] = h;
        ul[e] = f2bf(v - bf2f(h));
    }
    *(ushortx8*)(wth + tid * 8) = uh;
    *(ushortx8*)(wtl + tid * 8) = ul;
}

// ---------------------------------------------------------------------------
// Kernel 1: x = feat @ W via split-bf16 MFMA (held constant this round).
// ---------------------------------------------------------------------------
__global__ __launch_bounds__(64, 4) void k1_mfma(
    const float* __restrict__ feat, const unsigned short* __restrict__ wth,
    const unsigned short* __restrict__ wtl, unsigned short* __restrict__ xh,
    unsigned short* __restrict__ xl, int n) {
    __shared__ float s_x[16 * 132];
    int l = threadIdx.x;
    int m = l & 15, q = l >> 4;
    int r0 = blockIdx.x * 16;

    bf16x8 ah[4], al[4];
#pragma unroll
    for (int kt = 0; kt < 4; ++kt) {
        float vv[8];
        if (r0 + m < n) {
            const float* src = feat + (size_t)(r0 + m) * 128 + kt * 32 + q * 8;
            float4 v0 = *(const float4*)src;
            float4 v1 = *(const float4*)(src + 4);
            vv[0] = v0.x; vv[1] = v0.y; vv[2] = v0.z; vv[3] = v0.w;
            vv[4] = v1.x; vv[5] = v1.y; vv[6] = v1.z; vv[7] = v1.w;
        } else {
#pragma unroll
            for (int e = 0; e < 8; ++e) vv[e] = 0.0f;
        }
        ushortx8 uh, ul;
#pragma unroll
        for (int e = 0; e < 8; ++e) {
            unsigned short h = f2bf(vv[e]);
            uh[e] = h;
            ul[e] = f2bf(vv[e] - bf2f(h));
        }
        ah[kt] = __builtin_bit_cast(bf16x8, uh);
        al[kt] = __builtin_bit_cast(bf16x8, ul);
    }

#pragma unroll 2
    for (int nt = 0; nt < 8; ++nt) {
        floatx4 a = (floatx4){0.f, 0.f, 0.f, 0.f};
#pragma unroll
        for (int kt = 0; kt < 4; ++kt) {
            int fo = ((nt * 4 + kt) * 64 + l) * 8;
            bf16x8 bh = *(const bf16x8*)(wth + fo);
            bf16x8 bl = *(const bf16x8*)(wtl + fo);
            a = __builtin_amdgcn_mfma_f32_16x16x32_bf16(ah[kt], bh, a, 0, 0, 0);
            a = __builtin_amdgcn_mfma_f32_16x16x32_bf16(ah[kt], bl, a, 0, 0, 0);
            a = __builtin_amdgcn_mfma_f32_16x16x32_bf16(al[kt], bh, a, 0, 0, 0);
        }
#pragma unroll
        for (int r = 0; r < 4; ++r)
            s_x[(q * 4 + r) * 132 + nt * 16 + m] = a[r];
    }
    __syncthreads();

#pragma unroll
    for (int rr = 0; rr < 2; ++rr) {
        int row = rr * 8 + (l >> 3);
        int c0 = (l & 7) * 16;
        if (r0 + row < n) {
            float vv[16];
#pragma unroll
            for (int j = 0; j < 4; ++j) {
                float4 v = *(const float4*)&s_x[row * 132 + c0 + j * 4];
                vv[j * 4 + 0] = v.x; vv[j * 4 + 1] = v.y;
                vv[j * 4 + 2] = v.z; vv[j * 4 + 3] = v.w;
            }
            unsigned uh[8], ul[8];
#pragma unroll
            for (int p = 0; p < 8; ++p) {
                unsigned short h0 = f2bf(vv[2 * p]);
                unsigned short h1 = f2bf(vv[2 * p + 1]);
                unsigned short l0 = f2bf(vv[2 * p] - bf2f(h0));
                unsigned short l1 = f2bf(vv[2 * p + 1] - bf2f(h1));
                uh[p] = (unsigned)h0 | ((unsigned)h1 << 16);
                ul[p] = (unsigned)l0 | ((unsigned)l1 << 16);
            }
            size_t off = (size_t)(r0 + row) * 128 + c0;
            *(uint4*)(xh + off) = make_uint4(uh[0], uh[1], uh[2], uh[3]);
            *(uint4*)(xh + off + 8) = make_uint4(uh[4], uh[5], uh[6], uh[7]);
            *(uint4*)(xl + off) = make_uint4(ul[0], ul[1], ul[2], ul[3]);
            *(uint4*)(xl + off + 8) = make_uint4(ul[4], ul[5], ul[6], ul[7]);
        }
    }
}

// ---------------------------------------------------------------------------
// Kernel 2: one wave per node, TWO waves per 128-thread block. Single-variable
// experiment vs the spilling rounds: identical correctness-proven round-3 body,
// but block 256->128 and launch_bounds (256,6)->(128,4). (128,4) keeps the
// VGPR cap at 512/4=128 — the same cap as the never-spilling 64-thread config
// (52 VGPR). If the round-1/3 spill (VGPR=40 + ~700MB scratch WRITE) was the
// waves_per_eu=6 cap, it disappears now; if multi-wave blocks themselves
// trigger it, the fingerprint recurs and we lock 64-thread blocks for good.
// LDS ~6.3 KB/block -> residency capped by HW workgroup limit, not LDS.
// ---------------------------------------------------------------------------
__global__ __launch_bounds__(128, 4) void k2_conv(
    const float* __restrict__ ew, const int* __restrict__ nbr,
    const float* __restrict__ bias, const unsigned short* __restrict__ xh,
    const unsigned short* __restrict__ xl, float* __restrict__ outp, int n) {
    __shared__ float s_w[2][52];
    __shared__ int s_nb[2][52];
    __shared__ float s_tw[2][32];
    __shared__ int s_id[2][32];
    __shared__ float s_diag[2][32];
    __shared__ float s_dist[2][32];
    __shared__ float s_omega[2][32];
    __shared__ float s_red[2][4 * 130];  // 4 m-classes x 128 cols (+pad)

    int wv = threadIdx.x >> 6;  // 0..1
    int l = threadIdx.x & 63;
    int i = blockIdx.x * 2 + wv;
    if (i >= n) i = n - 1;  // duplicate compute of last node (benign same-value write)

    // A: candidates = 48 neighbors + self loop (weight 1.0)
    if (l < DEG + 1) {
        bool self = (l == DEG);
        s_w[wv][l] = self ? 1.0f : ew[(size_t)i * DEG + l];
        s_nb[wv][l] = self ? i : nbr[(size_t)i * DEG + l];
    }
    __syncthreads();

    // B: rank-based top-k (exact jax.lax.top_k tie semantics); rank == slot
    if (l < DEG + 1) {
        float wj = s_w[wv][l];
        int rank = 0;
#pragma unroll
        for (int t2 = 0; t2 < DEG + 1; ++t2) {
            float wt = s_w[wv][t2];
            rank += (wt > wj) || ((wt == wj) && (t2 < l)) ? 1 : 0;
        }
        if (rank < TOPK) {
            s_tw[wv][rank] = wj;
            s_id[wv][rank] = s_nb[wv][l];
        }
    }
    __syncthreads();

    // C: gather fragment pointers; compiler may rematerialize loads in G
    // (it chose exactly that at VGPR=52 in the known-good round).
    int m = l & 15;
    int q = l >> 4;
    int row0 = s_id[wv][m];
    int row1 = s_id[wv][16 + m];
    const __bf16* gh0 = (const __bf16*)(xh + (size_t)row0 * 128) + q * 8;
    const __bf16* gh1 = (const __bf16*)(xh + (size_t)row1 * 128) + q * 8;
    const __bf16* gl0 = (const __bf16*)(xl + (size_t)row0 * 128) + q * 8;
    const __bf16* gl1 = (const __bf16*)(xl + (size_t)row1 * 128) + q * 8;

    bf16x8 H0[4], H1[4], L0[4], L1[4];
#pragma unroll
    for (int kt = 0; kt < 4; ++kt) {
        H0[kt] = *(const bf16x8*)(gh0 + kt * 32);
        H1[kt] = *(const bf16x8*)(gh1 + kt * 32);
        L0[kt] = *(const bf16x8*)(gl0 + kt * 32);
        L1[kt] = *(const bf16x8*)(gl1 + kt * 32);
    }

    // D: Gram = X*X^T with X ~= H + L: G = HH^T + HL^T + LH^T
    floatx4 acc[2][2];
#pragma unroll
    for (int a = 0; a < 2; ++a)
#pragma unroll
        for (int b = 0; b < 2; ++b) acc[a][b] = (floatx4){0.f, 0.f, 0.f, 0.f};

#pragma unroll
    for (int kt = 0; kt < 4; ++kt) {
        bf16x8 h0 = H0[kt], h1 = H1[kt], l0 = L0[kt], l1 = L1[kt];
        acc[0][0] = __builtin_amdgcn_mfma_f32_16x16x32_bf16(h0, h0, acc[0][0], 0, 0, 0);
        acc[0][0] = __builtin_amdgcn_mfma_f32_16x16x32_bf16(h0, l0, acc[0][0], 0, 0, 0);
        acc[0][0] = __builtin_amdgcn_mfma_f32_16x16x32_bf16(l0, h0, acc[0][0], 0, 0, 0);
        acc[0][1] = __builtin_amdgcn_mfma_f32_16x16x32_bf16(h0, h1, acc[0][1], 0, 0, 0);
        acc[0][1] = __builtin_amdgcn_mfma_f32_16x16x32_bf16(h0, l1, acc[0][1], 0, 0, 0);
        acc[0][1] = __builtin_amdgcn_mfma_f32_16x16x32_bf16(l0, h1, acc[0][1], 0, 0, 0);
        acc[1][0] = __builtin_amdgcn_mfma_f32_16x16x32_bf16(h1, h0, acc[1][0], 0, 0, 0);
        acc[1][0] = __builtin_amdgcn_mfma_f32_16x16x32_bf16(h1, l0, acc[1][0], 0, 0, 0);
        acc[1][0] = __builtin_amdgcn_mfma_f32_16x16x32_bf16(l1, h0, acc[1][0], 0, 0, 0);
        acc[1][1] = __builtin_amdgcn_mfma_f32_16x16x32_bf16(h1, h1, acc[1][1], 0, 0, 0);
        acc[1][1] = __builtin_amdgcn_mfma_f32_16x16x32_bf16(h1, l1, acc[1][1], 0, 0, 0);
        acc[1][1] = __builtin_amdgcn_mfma_f32_16x16x32_bf16(l1, h1, acc[1][1], 0, 0, 0);
    }

    // D2: extract diagonal (sq) from Gram so that d2_aa == 0 exactly
    if (q == (m >> 2)) {
        int rd = m & 3;
        s_diag[wv][m] = acc[0][0][rd];
        s_diag[wv][16 + m] = acc[1][1][rd];
    }
    __syncthreads();

    // E: dist[a] = sum_b tw[b] * sqrt(d2 masked by d2>0)
    {
        float db0 = s_diag[wv][m];
        float db1 = s_diag[wv][16 + m];
        float tw0 = s_tw[wv][m];
        float tw1 = s_tw[wv][16 + m];
#pragma unroll
        for (int ma = 0; ma < 2; ++ma) {
#pragma unroll
            for (int r = 0; r < 4; ++r) {
                int a = ma * 16 + q * 4 + r;
                float da = s_diag[wv][a];
                float g0 = acc[ma][0][r];
                float g1 = acc[ma][1][r];
                float d20 = da + db0 - 2.0f * g0;
                float d21 = da + db1 - 2.0f * g1;
                float t0 = (d20 > 0.0f) ? fast_sqrt(d20) : 0.0f;
                float t1 = (d21 > 0.0f) ? fast_sqrt(d21) : 0.0f;
                float v = tw0 * t0 + tw1 * t1;
                v += __shfl_xor(v, 1);
                v += __shfl_xor(v, 2);
                v += __shfl_xor(v, 4);
                v += __shfl_xor(v, 8);
                if (m == 0) s_dist[wv][a] = v;
            }
        }
    }
    __syncthreads();

    // F: omega = exp(-dist - max(-dist)) * tw, normalized
    {
        int k32 = l & 31;
        float s = s_dist[wv][k32];
        float mn = s;
        mn = fminf(mn, __shfl_xor(mn, 1));
        mn = fminf(mn, __shfl_xor(mn, 2));
        mn = fminf(mn, __shfl_xor(mn, 4));
        mn = fminf(mn, __shfl_xor(mn, 8));
        mn = fminf(mn, __shfl_xor(mn, 16));
        float e = fast_exp(mn - s) * s_tw[wv][k32];
        float sum = e;
        sum += __shfl_xor(sum, 1);
        sum += __shfl_xor(sum, 2);
        sum += __shfl_xor(sum, 4);
        sum += __shfl_xor(sum, 8);
        sum += __shfl_xor(sum, 16);
        float om = e * fast_rcp(sum);
        if (l < 32) s_omega[wv][l] = om;
    }
    __syncthreads();

    // G: register partials; pre-reduce over m via shfl_xor(8),(4) -> only 4
    // m-classes hit LDS (s_red 4x130). Immediate per-kt LDS store keeps live
    // ranges short.
    {
        float w0 = s_omega[wv][m];
        float w1 = s_omega[wv][16 + m];
#pragma unroll
        for (int kt = 0; kt < 4; ++kt) {
            float p[8];
#pragma unroll
            for (int e = 0; e < 8; ++e) {
                float x0 = (float)H0[kt][e] + (float)L0[kt][e];
                float x1 = (float)H1[kt][e] + (float)L1[kt][e];
                p[e] = w0 * x0 + w1 * x1;
            }
#pragma unroll
            for (int e = 0; e < 8; ++e) {
                p[e] += __shfl_xor(p[e], 8);
                p[e] += __shfl_xor(p[e], 4);
            }
            if (m < 4) {  // lane (q, m) now holds sum over {m, m+4, m+8, m+12}
                float* dst = &s_red[wv][m * 130 + kt * 32 + q * 8];
                *(float4*)dst = make_float4(p[0], p[1], p[2], p[3]);
                *(float4*)(dst + 4) = make_float4(p[4], p[5], p[6], p[7]);
            }
        }
    }
    __syncthreads();

    // Final: each lane sums the 4 m-class rows for its 2 columns + bias.
    {
        int d0 = 2 * l;
        float2 bb = *(const float2*)(bias + d0);
        float o0 = bb.x, o1 = bb.y;
#pragma unroll
        for (int r = 0; r < 4; ++r) {
            float2 pr = *(const float2*)&s_red[wv][r * 130 + d0];
            o0 += pr.x;
            o1 += pr.y;
        }
        *(float2*)(outp + (size_t)i * 128 + d0) = make_float2(o0, o1);
    }
}

extern "C" void kernel_launch(void* const* d_in, const int* in_sizes, int n_in,
                              void* d_out, int out_size, void* d_ws, size_t ws_size,
                              hipStream_t stream) {
    const float* feat = (const float*)d_in[0];
    const float* ew = (const float*)d_in[1];
    const float* weight = (const float*)d_in[2];
    const float* bias = (const float*)d_in[3];
    const int* nbr = (const int*)d_in[4];
    float* outp = (float*)d_out;
    int n = in_sizes[0] / NNODE_DIN;  // 50000

    unsigned short* xh = (unsigned short*)d_ws;            // n x 128 bf16
    unsigned short* xl = xh + (size_t)n * NNODE_DOUT;      // n x 128 bf16
    unsigned short* wth = xl + (size_t)n * NNODE_DOUT;     // 2048 frags x 16B
    unsigned short* wtl = wth + 2048 * 8;

    hipLaunchKernelGGL(k0_wprep, dim3(8), dim3(256), 0, stream, weight, wth, wtl);
    int grid1 = (n + 15) / 16;
    hipLaunchKernelGGL(k1_mfma, dim3(grid1), dim3(64), 0, stream, feat, wth, wtl, xh, xl, n);
    int grid2 = (n + 1) / 2;
    hipLaunchKernelGGL(k2_conv, dim3(grid2), dim3(128), 0, stream, ew, nbr, bias, xh, xl, outp, n);
}

// Round 5
// 235.179 us; speedup vs baseline: 1.8661x; 1.0171x over previous
//
#include <hip/hip_runtime.h>
#include <hip/hip_bf16.h>

// Problem constants (match reference)
#define NNODE_DIN 128
#define NNODE_DOUT 128
#define DEG 48
#define TOPK 32

typedef __bf16 bf16x8 __attribute__((ext_vector_type(8)));
typedef unsigned short ushortx8 __attribute__((ext_vector_type(8)));
typedef float floatx4 __attribute__((ext_vector_type(4)));

__device__ inline unsigned short f2bf(float f) {
    __bf16 h = (__bf16)f;
    return __builtin_bit_cast(unsigned short, h);
}
__device__ inline float bf2f(unsigned short u) {
    unsigned v = ((unsigned)u) << 16;
    return __builtin_bit_cast(float, v);
}
// Raw transcendentals: proven correct in rounds 1, 3, 4 (absmax unchanged).
__device__ inline float fast_sqrt(float x) {
    float r; asm("v_sqrt_f32 %0, %1" : "=v"(r) : "v"(x)); return r;
}
__device__ inline float fast_exp(float x) {  // e^x, x <= 0 here (no overflow path)
    float t = x * 1.44269504088896341f;
    float r; asm("v_exp_f32 %0, %1" : "=v"(r) : "v"(t)); return r;
}
__device__ inline float fast_rcp(float x) {
    float r; asm("v_rcp_f32 %0, %1" : "=v"(r) : "v"(x)); return r;
}

// ---------------------------------------------------------------------------
// Kernel 0: pre-swizzle W^T into split-bf16 MFMA B-fragments in k1's load
// order. frag (nt,kt,lane) holds W[k][n], n = nt*16+(lane&15),
// k = kt*32+(lane>>4)*8+e. 2048 frags x 16 B per array (hi, lo).
// ---------------------------------------------------------------------------
__global__ __launch_bounds__(256) void k0_wprep(
    const float* __restrict__ w, unsigned short* __restrict__ wth,
    unsigned short* __restrict__ wtl) {
    int tid = blockIdx.x * 256 + threadIdx.x;  // 0..2047
    int lane = tid & 63;
    int kt = (tid >> 6) & 3;
    int nt = tid >> 8;
    int m = lane & 15, q = lane >> 4;
    int nn = nt * 16 + m;
    int k0 = kt * 32 + q * 8;
    ushortx8 uh, ul;
#pragma unroll
    for (int e = 0; e < 8; ++e) {
        float v = w[(size_t)(k0 + e) * 128 + nn];
        unsigned short h = f2bf(v);
        uh[e] = h;
        ul[e] = f2bf(v - bf2f(h));
    }
    *(ushortx8*)(wth + tid * 8) = uh;
    *(ushortx8*)(wtl + tid * 8) = ul;
}

// ---------------------------------------------------------------------------
// Kernel 1: x = feat @ W via split-bf16 MFMA (held constant this round).
// ---------------------------------------------------------------------------
__global__ __launch_bounds__(64, 4) void k1_mfma(
    const float* __restrict__ feat, const unsigned short* __restrict__ wth,
    const unsigned short* __restrict__ wtl, unsigned short* __restrict__ xh,
    unsigned short* __restrict__ xl, int n) {
    __shared__ float s_x[16 * 132];
    int l = threadIdx.x;
    int m = l & 15, q = l >> 4;
    int r0 = blockIdx.x * 16;

    bf16x8 ah[4], al[4];
#pragma unroll
    for (int kt = 0; kt < 4; ++kt) {
        float vv[8];
        if (r0 + m < n) {
            const float* src = feat + (size_t)(r0 + m) * 128 + kt * 32 + q * 8;
            float4 v0 = *(const float4*)src;
            float4 v1 = *(const float4*)(src + 4);
            vv[0] = v0.x; vv[1] = v0.y; vv[2] = v0.z; vv[3] = v0.w;
            vv[4] = v1.x; vv[5] = v1.y; vv[6] = v1.z; vv[7] = v1.w;
        } else {
#pragma unroll
            for (int e = 0; e < 8; ++e) vv[e] = 0.0f;
        }
        ushortx8 uh, ul;
#pragma unroll
        for (int e = 0; e < 8; ++e) {
            unsigned short h = f2bf(vv[e]);
            uh[e] = h;
            ul[e] = f2bf(vv[e] - bf2f(h));
        }
        ah[kt] = __builtin_bit_cast(bf16x8, uh);
        al[kt] = __builtin_bit_cast(bf16x8, ul);
    }

#pragma unroll 2
    for (int nt = 0; nt < 8; ++nt) {
        floatx4 a = (floatx4){0.f, 0.f, 0.f, 0.f};
#pragma unroll
        for (int kt = 0; kt < 4; ++kt) {
            int fo = ((nt * 4 + kt) * 64 + l) * 8;
            bf16x8 bh = *(const bf16x8*)(wth + fo);
            bf16x8 bl = *(const bf16x8*)(wtl + fo);
            a = __builtin_amdgcn_mfma_f32_16x16x32_bf16(ah[kt], bh, a, 0, 0, 0);
            a = __builtin_amdgcn_mfma_f32_16x16x32_bf16(ah[kt], bl, a, 0, 0, 0);
            a = __builtin_amdgcn_mfma_f32_16x16x32_bf16(al[kt], bh, a, 0, 0, 0);
        }
#pragma unroll
        for (int r = 0; r < 4; ++r)
            s_x[(q * 4 + r) * 132 + nt * 16 + m] = a[r];
    }
    __syncthreads();

#pragma unroll
    for (int rr = 0; rr < 2; ++rr) {
        int row = rr * 8 + (l >> 3);
        int c0 = (l & 7) * 16;
        if (r0 + row < n) {
            float vv[16];
#pragma unroll
            for (int j = 0; j < 4; ++j) {
                float4 v = *(const float4*)&s_x[row * 132 + c0 + j * 4];
                vv[j * 4 + 0] = v.x; vv[j * 4 + 1] = v.y;
                vv[j * 4 + 2] = v.z; vv[j * 4 + 3] = v.w;
            }
            unsigned uh[8], ul[8];
#pragma unroll
            for (int p = 0; p < 8; ++p) {
                unsigned short h0 = f2bf(vv[2 * p]);
                unsigned short h1 = f2bf(vv[2 * p + 1]);
                unsigned short l0 = f2bf(vv[2 * p] - bf2f(h0));
                unsigned short l1 = f2bf(vv[2 * p + 1] - bf2f(h1));
                uh[p] = (unsigned)h0 | ((unsigned)h1 << 16);
                ul[p] = (unsigned)l0 | ((unsigned)l1 << 16);
            }
            size_t off = (size_t)(r0 + row) * 128 + c0;
            *(uint4*)(xh + off) = make_uint4(uh[0], uh[1], uh[2], uh[3]);
            *(uint4*)(xh + off + 8) = make_uint4(uh[4], uh[5], uh[6], uh[7]);
            *(uint4*)(xl + off) = make_uint4(ul[0], ul[1], ul[2], ul[3]);
            *(uint4*)(xl + off + 8) = make_uint4(ul[4], ul[5], ul[6], ul[7]);
        }
    }
}

// ---------------------------------------------------------------------------
// Kernel 2: one wave per node, 64-thread blocks (occupancy experiments
// concluded: 64-thr/128-thr/256-thr all land at 41-63% occ with IDENTICAL or
// worse time — occupancy was never the lever). NEW this round: the fragment
// registers are PINNED with an opaque asm hold after the phase-C gather.
// Rationale: VGPR=52 in all passing rounds proves the compiler rematerialized
// the 16 divergent gather loads in phase G -> two full random-gather passes
// per node over a 25.6MB table that misses per-XCD L2 (4MB). The pin forces
// one pass (compiler must hold 64 VGPRs; cap is 128 at launch_bounds(64,4),
// body needs ~110). G-phase keeps the proven round-3/4 shfl pre-reduce +
// s_red[4*130] (LDS ~3.2 KB).
// ---------------------------------------------------------------------------
__global__ __launch_bounds__(64, 4) void k2_conv(
    const float* __restrict__ ew, const int* __restrict__ nbr,
    const float* __restrict__ bias, const unsigned short* __restrict__ xh,
    const unsigned short* __restrict__ xl, float* __restrict__ outp, int n) {
    __shared__ float s_w[52];
    __shared__ int s_nb[52];
    __shared__ float s_tw[32];
    __shared__ int s_id[32];
    __shared__ float s_diag[32];
    __shared__ float s_dist[32];
    __shared__ float s_omega[32];
    __shared__ float s_red[4 * 130];  // 4 m-classes x 128 cols (+pad)

    int i = blockIdx.x;
    int l = threadIdx.x;

    // A: candidates = 48 neighbors + self loop (weight 1.0)
    if (l < DEG + 1) {
        bool self = (l == DEG);
        s_w[l] = self ? 1.0f : ew[(size_t)i * DEG + l];
        s_nb[l] = self ? i : nbr[(size_t)i * DEG + l];
    }
    __syncthreads();

    // B: rank-based top-k (exact jax.lax.top_k tie semantics); rank == slot
    if (l < DEG + 1) {
        float wj = s_w[l];
        int rank = 0;
#pragma unroll
        for (int t2 = 0; t2 < DEG + 1; ++t2) {
            float wt = s_w[t2];
            rank += (wt > wj) || ((wt == wj) && (t2 < l)) ? 1 : 0;
        }
        if (rank < TOPK) {
            s_tw[rank] = wj;
            s_id[rank] = s_nb[l];
        }
    }
    __syncthreads();

    // C: gather all 16 fragments ONCE; pin them in registers with an opaque
    // asm hold so the compiler cannot rematerialize the loads in phase G.
    int m = l & 15;
    int q = l >> 4;
    int row0 = s_id[m];
    int row1 = s_id[16 + m];
    const __bf16* gh0 = (const __bf16*)(xh + (size_t)row0 * 128) + q * 8;
    const __bf16* gh1 = (const __bf16*)(xh + (size_t)row1 * 128) + q * 8;
    const __bf16* gl0 = (const __bf16*)(xl + (size_t)row0 * 128) + q * 8;
    const __bf16* gl1 = (const __bf16*)(xl + (size_t)row1 * 128) + q * 8;

    bf16x8 H0[4], H1[4], L0[4], L1[4];
#pragma unroll
    for (int kt = 0; kt < 4; ++kt) {
        H0[kt] = *(const bf16x8*)(gh0 + kt * 32);
        H1[kt] = *(const bf16x8*)(gh1 + kt * 32);
        L0[kt] = *(const bf16x8*)(gl0 + kt * 32);
        L1[kt] = *(const bf16x8*)(gl1 + kt * 32);
    }
#pragma unroll
    for (int kt = 0; kt < 4; ++kt) {
        asm volatile("" : "+v"(H0[kt]), "+v"(H1[kt]), "+v"(L0[kt]), "+v"(L1[kt]));
    }

    // D: Gram = X*X^T with X ~= H + L: G = HH^T + HL^T + LH^T
    floatx4 acc[2][2];
#pragma unroll
    for (int a = 0; a < 2; ++a)
#pragma unroll
        for (int b = 0; b < 2; ++b) acc[a][b] = (floatx4){0.f, 0.f, 0.f, 0.f};

#pragma unroll
    for (int kt = 0; kt < 4; ++kt) {
        bf16x8 h0 = H0[kt], h1 = H1[kt], l0 = L0[kt], l1 = L1[kt];
        acc[0][0] = __builtin_amdgcn_mfma_f32_16x16x32_bf16(h0, h0, acc[0][0], 0, 0, 0);
        acc[0][0] = __builtin_amdgcn_mfma_f32_16x16x32_bf16(h0, l0, acc[0][0], 0, 0, 0);
        acc[0][0] = __builtin_amdgcn_mfma_f32_16x16x32_bf16(l0, h0, acc[0][0], 0, 0, 0);
        acc[0][1] = __builtin_amdgcn_mfma_f32_16x16x32_bf16(h0, h1, acc[0][1], 0, 0, 0);
        acc[0][1] = __builtin_amdgcn_mfma_f32_16x16x32_bf16(h0, l1, acc[0][1], 0, 0, 0);
        acc[0][1] = __builtin_amdgcn_mfma_f32_16x16x32_bf16(l0, h1, acc[0][1], 0, 0, 0);
        acc[1][0] = __builtin_amdgcn_mfma_f32_16x16x32_bf16(h1, h0, acc[1][0], 0, 0, 0);
        acc[1][0] = __builtin_amdgcn_mfma_f32_16x16x32_bf16(h1, l0, acc[1][0], 0, 0, 0);
        acc[1][0] = __builtin_amdgcn_mfma_f32_16x16x32_bf16(l1, h0, acc[1][0], 0, 0, 0);
        acc[1][1] = __builtin_amdgcn_mfma_f32_16x16x32_bf16(h1, h1, acc[1][1], 0, 0, 0);
        acc[1][1] = __builtin_amdgcn_mfma_f32_16x16x32_bf16(h1, l1, acc[1][1], 0, 0, 0);
        acc[1][1] = __builtin_amdgcn_mfma_f32_16x16x32_bf16(l1, h1, acc[1][1], 0, 0, 0);
    }

    // D2: extract diagonal (sq) from Gram so that d2_aa == 0 exactly
    if (q == (m >> 2)) {
        int rd = m & 3;
        s_diag[m] = acc[0][0][rd];
        s_diag[16 + m] = acc[1][1][rd];
    }
    __syncthreads();

    // E: dist[a] = sum_b tw[b] * sqrt(d2 masked by d2>0)
    {
        float db0 = s_diag[m];
        float db1 = s_diag[16 + m];
        float tw0 = s_tw[m];
        float tw1 = s_tw[16 + m];
#pragma unroll
        for (int ma = 0; ma < 2; ++ma) {
#pragma unroll
            for (int r = 0; r < 4; ++r) {
                int a = ma * 16 + q * 4 + r;
                float da = s_diag[a];
                float g0 = acc[ma][0][r];
                float g1 = acc[ma][1][r];
                float d20 = da + db0 - 2.0f * g0;
                float d21 = da + db1 - 2.0f * g1;
                float t0 = (d20 > 0.0f) ? fast_sqrt(d20) : 0.0f;
                float t1 = (d21 > 0.0f) ? fast_sqrt(d21) : 0.0f;
                float v = tw0 * t0 + tw1 * t1;
                v += __shfl_xor(v, 1);
                v += __shfl_xor(v, 2);
                v += __shfl_xor(v, 4);
                v += __shfl_xor(v, 8);
                if (m == 0) s_dist[a] = v;
            }
        }
    }
    __syncthreads();

    // F: omega = exp(-dist - max(-dist)) * tw, normalized
    {
        int k32 = l & 31;
        float s = s_dist[k32];
        float mn = s;
        mn = fminf(mn, __shfl_xor(mn, 1));
        mn = fminf(mn, __shfl_xor(mn, 2));
        mn = fminf(mn, __shfl_xor(mn, 4));
        mn = fminf(mn, __shfl_xor(mn, 8));
        mn = fminf(mn, __shfl_xor(mn, 16));
        float e = fast_exp(mn - s) * s_tw[k32];
        float sum = e;
        sum += __shfl_xor(sum, 1);
        sum += __shfl_xor(sum, 2);
        sum += __shfl_xor(sum, 4);
        sum += __shfl_xor(sum, 8);
        sum += __shfl_xor(sum, 16);
        float om = e * fast_rcp(sum);
        if (l < 32) s_omega[l] = om;
    }
    __syncthreads();

    // G: aggregate from the PINNED registers (no global re-read); pre-reduce
    // over m via shfl_xor(8),(4) -> 4 m-classes hit LDS (s_red 4x130).
    {
        float w0 = s_omega[m];
        float w1 = s_omega[16 + m];
#pragma unroll
        for (int kt = 0; kt < 4; ++kt) {
            float p[8];
#pragma unroll
            for (int e = 0; e < 8; ++e) {
                float x0 = (float)H0[kt][e] + (float)L0[kt][e];
                float x1 = (float)H1[kt][e] + (float)L1[kt][e];
                p[e] = w0 * x0 + w1 * x1;
            }
#pragma unroll
            for (int e = 0; e < 8; ++e) {
                p[e] += __shfl_xor(p[e], 8);
                p[e] += __shfl_xor(p[e], 4);
            }
            if (m < 4) {  // lane (q, m) now holds sum over {m, m+4, m+8, m+12}
                float* dst = &s_red[m * 130 + kt * 32 + q * 8];
                *(float4*)dst = make_float4(p[0], p[1], p[2], p[3]);
                *(float4*)(dst + 4) = make_float4(p[4], p[5], p[6], p[7]);
            }
        }
    }
    __syncthreads();

    // Final: each lane sums the 4 m-class rows for its 2 columns + bias.
    {
        int d0 = 2 * l;
        float2 bb = *(const float2*)(bias + d0);
        float o0 = bb.x, o1 = bb.y;
#pragma unroll
        for (int r = 0; r < 4; ++r) {
            float2 pr = *(const float2*)&s_red[r * 130 + d0];
            o0 += pr.x;
            o1 += pr.y;
        }
        *(float2*)(outp + (size_t)i * 128 + d0) = make_float2(o0, o1);
    }
}

extern "C" void kernel_launch(void* const* d_in, const int* in_sizes, int n_in,
                              void* d_out, int out_size, void* d_ws, size_t ws_size,
                              hipStream_t stream) {
    const float* feat = (const float*)d_in[0];
    const float* ew = (const float*)d_in[1];
    const float* weight = (const float*)d_in[2];
    const float* bias = (const float*)d_in[3];
    const int* nbr = (const int*)d_in[4];
    float* outp = (float*)d_out;
    int n = in_sizes[0] / NNODE_DIN;  // 50000

    unsigned short* xh = (unsigned short*)d_ws;            // n x 128 bf16
    unsigned short* xl = xh + (size_t)n * NNODE_DOUT;      // n x 128 bf16
    unsigned short* wth = xl + (size_t)n * NNODE_DOUT;     // 2048 frags x 16B
    unsigned short* wtl = wth + 2048 * 8;

    hipLaunchKernelGGL(k0_wprep, dim3(8), dim3(256), 0, stream, weight, wth, wtl);
    int grid1 = (n + 15) / 16;
    hipLaunchKernelGGL(k1_mfma, dim3(grid1), dim3(64), 0, stream, feat, wth, wtl, xh, xl, n);
    hipLaunchKernelGGL(k2_conv, dim3(n), dim3(64), 0, stream, ew, nbr, bias, xh, xl, outp, n);
}

// Round 6
// 200.611 us; speedup vs baseline: 2.1876x; 1.1723x over previous
//
#include <hip/hip_runtime.h>
#include <hip/hip_bf16.h>

// Problem constants (match reference)
#define NNODE_DIN 128
#define NNODE_DOUT 128
#define DEG 48
#define TOPK 32

typedef _Float16 halfx8 __attribute__((ext_vector_type(8)));
typedef unsigned short ushortx8 __attribute__((ext_vector_type(8)));
typedef float floatx4 __attribute__((ext_vector_type(4)));

__device__ inline unsigned short f2h(float f) {
    _Float16 h = (_Float16)f;
    return __builtin_bit_cast(unsigned short, h);
}
__device__ inline float h2f(unsigned short u) {
    return (float)__builtin_bit_cast(_Float16, u);
}
// Raw transcendentals: proven correct in rounds 1, 3, 4, 5 (absmax unchanged).
__device__ inline float fast_sqrt(float x) {
    float r; asm("v_sqrt_f32 %0, %1" : "=v"(r) : "v"(x)); return r;
}
__device__ inline float fast_exp(float x) {  // e^x, x <= 0 here (no overflow path)
    float t = x * 1.44269504088896341f;
    float r; asm("v_exp_f32 %0, %1" : "=v"(r) : "v"(t)); return r;
}
__device__ inline float fast_rcp(float x) {
    float r; asm("v_rcp_f32 %0, %1" : "=v"(r) : "v"(x)); return r;
}

// ---------------------------------------------------------------------------
// Kernel 0: pre-swizzle W^T into split-FP16 MFMA B-fragments in k1's load
// order. frag (nt,kt,lane) holds W[k][n], n = nt*16+(lane&15),
// k = kt*32+(lane>>4)*8+e. fp16 split (h + residual l) carries ~21 mantissa
// bits — more than enough for the x GEMM.
// ---------------------------------------------------------------------------
__global__ __launch_bounds__(256) void k0_wprep(
    const float* __restrict__ w, unsigned short* __restrict__ wth,
    unsigned short* __restrict__ wtl) {
    int tid = blockIdx.x * 256 + threadIdx.x;  // 0..2047
    int lane = tid & 63;
    int kt = (tid >> 6) & 3;
    int nt = tid >> 8;
    int m = lane & 15, q = lane >> 4;
    int nn = nt * 16 + m;
    int k0 = kt * 32 + q * 8;
    ushortx8 uh, ul;
#pragma unroll
    for (int e = 0; e < 8; ++e) {
        float v = w[(size_t)(k0 + e) * 128 + nn];
        unsigned short h = f2h(v);
        uh[e] = h;
        ul[e] = f2h(v - h2f(h));
    }
    *(ushortx8*)(wth + tid * 8) = uh;
    *(ushortx8*)(wtl + tid * 8) = ul;
}

// ---------------------------------------------------------------------------
// Kernel 1: x = feat @ W via split-FP16 MFMA (structure proven through
// rounds 1-5; dtype switched bf16->fp16). Output: SINGLE fp16 table xf
// (halves k1's store traffic and, crucially, k2's gather traffic).
// ---------------------------------------------------------------------------
__global__ __launch_bounds__(64, 4) void k1_mfma(
    const float* __restrict__ feat, const unsigned short* __restrict__ wth,
    const unsigned short* __restrict__ wtl, unsigned short* __restrict__ xf,
    int n) {
    __shared__ float s_x[16 * 132];
    int l = threadIdx.x;
    int m = l & 15, q = l >> 4;
    int r0 = blockIdx.x * 16;

    halfx8 ah[4], al[4];
#pragma unroll
    for (int kt = 0; kt < 4; ++kt) {
        float vv[8];
        if (r0 + m < n) {
            const float* src = feat + (size_t)(r0 + m) * 128 + kt * 32 + q * 8;
            float4 v0 = *(const float4*)src;
            float4 v1 = *(const float4*)(src + 4);
            vv[0] = v0.x; vv[1] = v0.y; vv[2] = v0.z; vv[3] = v0.w;
            vv[4] = v1.x; vv[5] = v1.y; vv[6] = v1.z; vv[7] = v1.w;
        } else {
#pragma unroll
            for (int e = 0; e < 8; ++e) vv[e] = 0.0f;
        }
        ushortx8 uh, ul;
#pragma unroll
        for (int e = 0; e < 8; ++e) {
            unsigned short h = f2h(vv[e]);
            uh[e] = h;
            ul[e] = f2h(vv[e] - h2f(h));
        }
        ah[kt] = __builtin_bit_cast(halfx8, uh);
        al[kt] = __builtin_bit_cast(halfx8, ul);
    }

#pragma unroll 2
    for (int nt = 0; nt < 8; ++nt) {
        floatx4 a = (floatx4){0.f, 0.f, 0.f, 0.f};
#pragma unroll
        for (int kt = 0; kt < 4; ++kt) {
            int fo = ((nt * 4 + kt) * 64 + l) * 8;
            halfx8 bh = *(const halfx8*)(wth + fo);
            halfx8 bl = *(const halfx8*)(wtl + fo);
            a = __builtin_amdgcn_mfma_f32_16x16x32_f16(ah[kt], bh, a, 0, 0, 0);
            a = __builtin_amdgcn_mfma_f32_16x16x32_f16(ah[kt], bl, a, 0, 0, 0);
            a = __builtin_amdgcn_mfma_f32_16x16x32_f16(al[kt], bh, a, 0, 0, 0);
        }
        // D layout: a[r] = x[r0 + q*4 + r][nt*16 + m] -> stage transpose in LDS
#pragma unroll
        for (int r = 0; r < 4; ++r)
            s_x[(q * 4 + r) * 132 + nt * 16 + m] = a[r];
    }
    __syncthreads();

#pragma unroll
    for (int rr = 0; rr < 2; ++rr) {
        int row = rr * 8 + (l >> 3);
        int c0 = (l & 7) * 16;
        if (r0 + row < n) {
            float vv[16];
#pragma unroll
            for (int j = 0; j < 4; ++j) {
                float4 v = *(const float4*)&s_x[row * 132 + c0 + j * 4];
                vv[j * 4 + 0] = v.x; vv[j * 4 + 1] = v.y;
                vv[j * 4 + 2] = v.z; vv[j * 4 + 3] = v.w;
            }
            unsigned u[8];
#pragma unroll
            for (int p = 0; p < 8; ++p) {
                u[p] = (unsigned)f2h(vv[2 * p]) | ((unsigned)f2h(vv[2 * p + 1]) << 16);
            }
            size_t off = (size_t)(r0 + row) * 128 + c0;
            *(uint4*)(xf + off) = make_uint4(u[0], u[1], u[2], u[3]);
            *(uint4*)(xf + off + 8) = make_uint4(u[4], u[5], u[6], u[7]);
        }
    }
}

// ---------------------------------------------------------------------------
// Kernel 2: one wave per node, 64-thread blocks. ROUND-6 RESTRUCTURE per the
// gather-traffic theory (k2 invariant at ~150us across occupancy 39-63% and
// three epilogues; MFMA 11% / VALU 41% / 2.35 TB/s of L2-miss gather):
//   - x table is SINGLE fp16 (12.8 MB vs 25.6): gather bytes halve, XCD-L2
//     capacity hit rate ~doubles, Gram = 16 MFMAs (was 48).
//   - the 32 gathered rows are STAGED TO LDS in phase C; phase G aggregates
//     from LDS -> a second global gather pass is structurally impossible
//     (round-5 pin proved the compiler otherwise rematerializes the loads).
//   - G simplifies: lane l owns output cols {2l, 2l+1}; 32 broadcast-weight
//     fma steps from s_rows (2-way bank aliasing = free). No shfl, no s_red.
// ---------------------------------------------------------------------------
__global__ __launch_bounds__(64, 4) void k2_conv(
    const float* __restrict__ ew, const int* __restrict__ nbr,
    const float* __restrict__ bias, const unsigned short* __restrict__ xf,
    float* __restrict__ outp, int n) {
    __shared__ float s_w[52];
    __shared__ int s_nb[52];
    __shared__ float s_tw[32];
    __shared__ int s_id[32];
    __shared__ float s_diag[32];
    __shared__ float s_dist[32];
    __shared__ float s_omega[32];
    __shared__ _Float16 s_rows[32][128];  // 8 KB: the gathered neighborhood

    int i = blockIdx.x;
    int l = threadIdx.x;

    // A: candidates = 48 neighbors + self loop (weight 1.0)
    if (l < DEG + 1) {
        bool self = (l == DEG);
        s_w[l] = self ? 1.0f : ew[(size_t)i * DEG + l];
        s_nb[l] = self ? i : nbr[(size_t)i * DEG + l];
    }
    __syncthreads();

    // B: rank-based top-k (exact jax.lax.top_k tie semantics); rank == slot
    if (l < DEG + 1) {
        float wj = s_w[l];
        int rank = 0;
#pragma unroll
        for (int t2 = 0; t2 < DEG + 1; ++t2) {
            float wt = s_w[t2];
            rank += (wt > wj) || ((wt == wj) && (t2 < l)) ? 1 : 0;
        }
        if (rank < TOPK) {
            s_tw[rank] = wj;
            s_id[rank] = s_nb[l];
        }
    }
    __syncthreads();

    // C: gather the 8 fragments ONCE (one 16B dwordx4 per (row,kt) slice),
    // then stage them into LDS for the epilogue.
    int m = l & 15;
    int q = l >> 4;
    int row0 = s_id[m];
    int row1 = s_id[16 + m];
    const _Float16* g0 = (const _Float16*)xf + (size_t)row0 * 128 + q * 8;
    const _Float16* g1 = (const _Float16*)xf + (size_t)row1 * 128 + q * 8;

    halfx8 H0[4], H1[4];
#pragma unroll
    for (int kt = 0; kt < 4; ++kt) {
        H0[kt] = *(const halfx8*)(g0 + kt * 32);
        H1[kt] = *(const halfx8*)(g1 + kt * 32);
    }
#pragma unroll
    for (int kt = 0; kt < 4; ++kt) {
        *(halfx8*)&s_rows[m][kt * 32 + q * 8] = H0[kt];
        *(halfx8*)&s_rows[16 + m][kt * 32 + q * 8] = H1[kt];
    }

    // D: Gram = X*X^T directly in fp16 (fp32 accumulate)
    floatx4 acc[2][2];
#pragma unroll
    for (int a = 0; a < 2; ++a)
#pragma unroll
        for (int b = 0; b < 2; ++b) acc[a][b] = (floatx4){0.f, 0.f, 0.f, 0.f};

#pragma unroll
    for (int kt = 0; kt < 4; ++kt) {
        halfx8 h0 = H0[kt], h1 = H1[kt];
        acc[0][0] = __builtin_amdgcn_mfma_f32_16x16x32_f16(h0, h0, acc[0][0], 0, 0, 0);
        acc[0][1] = __builtin_amdgcn_mfma_f32_16x16x32_f16(h0, h1, acc[0][1], 0, 0, 0);
        acc[1][0] = __builtin_amdgcn_mfma_f32_16x16x32_f16(h1, h0, acc[1][0], 0, 0, 0);
        acc[1][1] = __builtin_amdgcn_mfma_f32_16x16x32_f16(h1, h1, acc[1][1], 0, 0, 0);
    }

    // D2: extract diagonal (sq) from Gram so that d2_aa == 0 exactly
    if (q == (m >> 2)) {
        int rd = m & 3;
        s_diag[m] = acc[0][0][rd];
        s_diag[16 + m] = acc[1][1][rd];
    }
    __syncthreads();

    // E: dist[a] = sum_b tw[b] * sqrt(d2 masked by d2>0)
    {
        float db0 = s_diag[m];
        float db1 = s_diag[16 + m];
        float tw0 = s_tw[m];
        float tw1 = s_tw[16 + m];
#pragma unroll
        for (int ma = 0; ma < 2; ++ma) {
#pragma unroll
            for (int r = 0; r < 4; ++r) {
                int a = ma * 16 + q * 4 + r;
                float da = s_diag[a];
                float g0v = acc[ma][0][r];
                float g1v = acc[ma][1][r];
                float d20 = da + db0 - 2.0f * g0v;
                float d21 = da + db1 - 2.0f * g1v;
                float t0 = (d20 > 0.0f) ? fast_sqrt(d20) : 0.0f;
                float t1 = (d21 > 0.0f) ? fast_sqrt(d21) : 0.0f;
                float v = tw0 * t0 + tw1 * t1;
                v += __shfl_xor(v, 1);
                v += __shfl_xor(v, 2);
                v += __shfl_xor(v, 4);
                v += __shfl_xor(v, 8);
                if (m == 0) s_dist[a] = v;
            }
        }
    }
    __syncthreads();

    // F: omega = exp(-dist - max(-dist)) * tw, normalized
    {
        int k32 = l & 31;
        float s = s_dist[k32];
        float mn = s;
        mn = fminf(mn, __shfl_xor(mn, 1));
        mn = fminf(mn, __shfl_xor(mn, 2));
        mn = fminf(mn, __shfl_xor(mn, 4));
        mn = fminf(mn, __shfl_xor(mn, 8));
        mn = fminf(mn, __shfl_xor(mn, 16));
        float e = fast_exp(mn - s) * s_tw[k32];
        float sum = e;
        sum += __shfl_xor(sum, 1);
        sum += __shfl_xor(sum, 2);
        sum += __shfl_xor(sum, 4);
        sum += __shfl_xor(sum, 8);
        sum += __shfl_xor(sum, 16);
        float om = e * fast_rcp(sum);
        if (l < 32) s_omega[l] = om;
    }
    __syncthreads();

    // G: aggregate from LDS — lane l owns output columns {2l, 2l+1}.
    // s_rows[b][2l]: 64 lanes read 256 consecutive bytes -> 2-way bank
    // aliasing (free). s_omega[b] is a broadcast. 32 fma steps, no shuffles.
    {
        int d0 = 2 * l;
        float2 bb = *(const float2*)(bias + d0);
        float o0 = bb.x, o1 = bb.y;
#pragma unroll
        for (int b = 0; b < 32; ++b) {
            float wb = s_omega[b];
            unsigned uu = *(const unsigned*)&s_rows[b][d0];
            o0 += wb * h2f((unsigned short)(uu & 0xffff));
            o1 += wb * h2f((unsigned short)(uu >> 16));
        }
        *(float2*)(outp + (size_t)i * 128 + d0) = make_float2(o0, o1);
    }
}

extern "C" void kernel_launch(void* const* d_in, const int* in_sizes, int n_in,
                              void* d_out, int out_size, void* d_ws, size_t ws_size,
                              hipStream_t stream) {
    const float* feat = (const float*)d_in[0];
    const float* ew = (const float*)d_in[1];
    const float* weight = (const float*)d_in[2];
    const float* bias = (const float*)d_in[3];
    const int* nbr = (const int*)d_in[4];
    float* outp = (float*)d_out;
    int n = in_sizes[0] / NNODE_DIN;  // 50000

    unsigned short* xf = (unsigned short*)d_ws;            // n x 128 fp16
    unsigned short* wth = xf + (size_t)n * NNODE_DOUT;     // 2048 frags x 16B
    unsigned short* wtl = wth + 2048 * 8;

    hipLaunchKernelGGL(k0_wprep, dim3(8), dim3(256), 0, stream, weight, wth, wtl);
    int grid1 = (n + 15) / 16;
    hipLaunchKernelGGL(k1_mfma, dim3(grid1), dim3(64), 0, stream, feat, wth, wtl, xf, n);
    hipLaunchKernelGGL(k2_conv, dim3(n), dim3(64), 0, stream, ew, nbr, bias, xf, outp, n);
}

// Round 7
// 191.833 us; speedup vs baseline: 2.2878x; 1.0458x over previous
//
#include <hip/hip_runtime.h>
#include <hip/hip_bf16.h>

// Problem constants (match reference)
#define NNODE_DIN 128
#define NNODE_DOUT 128
#define DEG 48
#define TOPK 32

typedef _Float16 halfx8 __attribute__((ext_vector_type(8)));
typedef unsigned short ushortx8 __attribute__((ext_vector_type(8)));
typedef float floatx4 __attribute__((ext_vector_type(4)));

__device__ inline unsigned short f2h(float f) {
    _Float16 h = (_Float16)f;
    return __builtin_bit_cast(unsigned short, h);
}
__device__ inline float h2f(unsigned short u) {
    return (float)__builtin_bit_cast(_Float16, u);
}
// Raw transcendentals: proven correct in rounds 1-6 (absmax unchanged).
__device__ inline float fast_sqrt(float x) {
    float r; asm("v_sqrt_f32 %0, %1" : "=v"(r) : "v"(x)); return r;
}
__device__ inline float fast_exp(float x) {  // e^x, x <= 0 here (no overflow path)
    float t = x * 1.44269504088896341f;
    float r; asm("v_exp_f32 %0, %1" : "=v"(r) : "v"(t)); return r;
}
__device__ inline float fast_rcp(float x) {
    float r; asm("v_rcp_f32 %0, %1" : "=v"(r) : "v"(x)); return r;
}

// ---------------------------------------------------------------------------
// Kernel 0: pre-swizzle W^T into split-FP16 MFMA B-fragments in k1's load
// order. frag (nt,kt,lane) holds W[k][n], n = nt*16+(lane&15),
// k = kt*32+(lane>>4)*8+e. (unchanged from round 6)
// ---------------------------------------------------------------------------
__global__ __launch_bounds__(256) void k0_wprep(
    const float* __restrict__ w, unsigned short* __restrict__ wth,
    unsigned short* __restrict__ wtl) {
    int tid = blockIdx.x * 256 + threadIdx.x;  // 0..2047
    int lane = tid & 63;
    int kt = (tid >> 6) & 3;
    int nt = tid >> 8;
    int m = lane & 15, q = lane >> 4;
    int nn = nt * 16 + m;
    int k0 = kt * 32 + q * 8;
    ushortx8 uh, ul;
#pragma unroll
    for (int e = 0; e < 8; ++e) {
        float v = w[(size_t)(k0 + e) * 128 + nn];
        unsigned short h = f2h(v);
        uh[e] = h;
        ul[e] = f2h(v - h2f(h));
    }
    *(ushortx8*)(wth + tid * 8) = uh;
    *(ushortx8*)(wtl + tid * 8) = ul;
}

// ---------------------------------------------------------------------------
// Kernel 1: x = feat @ W via split-FP16 MFMA. ROUND-7 RESTRUCTURE per the
// latency-underfill theory (non-k2 leg pinned at ~84us across 7 measurements;
// old shape: 3125 single-wave blocks = ~3 waves/SIMD, 96-MFMA serial acc
// chain + 64 B-loads per wave). Now: 4 waves per 16-row block, wave w owns
// nt in {2w, 2w+1} -> 24 MFMAs + 16 B-loads per wave, 12500 waves (~28/CU).
// Each wave re-loads the same 16 feat rows (L1/L2 hits; HBM unchanged).
// Epilogue: 256 threads, one uint4 store each (conflict-free: start banks
// 4row+8col cover all 32 banks evenly 8-deep).
// ---------------------------------------------------------------------------
__global__ __launch_bounds__(256, 4) void k1_mfma(
    const float* __restrict__ feat, const unsigned short* __restrict__ wth,
    const unsigned short* __restrict__ wtl, unsigned short* __restrict__ xf,
    int n) {
    __shared__ float s_x[16 * 132];
    int t = threadIdx.x;
    int w = t >> 6;           // wave 0..3
    int l = t & 63;
    int m = l & 15, q = l >> 4;
    int r0 = blockIdx.x * 16;

    // A-fragments: feat rows r0+m, split into hi/lo fp16 (all 4 waves load
    // the same rows -> 3 of 4 are L1/L2 hits).
    halfx8 ah[4], al[4];
#pragma unroll
    for (int kt = 0; kt < 4; ++kt) {
        float vv[8];
        if (r0 + m < n) {
            const float* src = feat + (size_t)(r0 + m) * 128 + kt * 32 + q * 8;
            float4 v0 = *(const float4*)src;
            float4 v1 = *(const float4*)(src + 4);
            vv[0] = v0.x; vv[1] = v0.y; vv[2] = v0.z; vv[3] = v0.w;
            vv[4] = v1.x; vv[5] = v1.y; vv[6] = v1.z; vv[7] = v1.w;
        } else {
#pragma unroll
            for (int e = 0; e < 8; ++e) vv[e] = 0.0f;
        }
        ushortx8 uh, ul;
#pragma unroll
        for (int e = 0; e < 8; ++e) {
            unsigned short h = f2h(vv[e]);
            uh[e] = h;
            ul[e] = f2h(vv[e] - h2f(h));
        }
        ah[kt] = __builtin_bit_cast(halfx8, uh);
        al[kt] = __builtin_bit_cast(halfx8, ul);
    }

    // Two nt columns per wave.
#pragma unroll
    for (int nn = 0; nn < 2; ++nn) {
        int nt = 2 * w + nn;
        floatx4 a = (floatx4){0.f, 0.f, 0.f, 0.f};
#pragma unroll
        for (int kt = 0; kt < 4; ++kt) {
            int fo = ((nt * 4 + kt) * 64 + l) * 8;
            halfx8 bh = *(const halfx8*)(wth + fo);
            halfx8 bl = *(const halfx8*)(wtl + fo);
            a = __builtin_amdgcn_mfma_f32_16x16x32_f16(ah[kt], bh, a, 0, 0, 0);
            a = __builtin_amdgcn_mfma_f32_16x16x32_f16(ah[kt], bl, a, 0, 0, 0);
            a = __builtin_amdgcn_mfma_f32_16x16x32_f16(al[kt], bh, a, 0, 0, 0);
        }
        // D layout: a[r] = x[r0 + q*4 + r][nt*16 + m]; waves write disjoint
        // column ranges. Bank (16q + m)%32: 2 lanes/bank = free.
#pragma unroll
        for (int r = 0; r < 4; ++r)
            s_x[(q * 4 + r) * 132 + nt * 16 + m] = a[r];
    }
    __syncthreads();

    // Epilogue: thread t -> row = t>>4, cols (t&15)*8 .. +7; one uint4 store.
    {
        int row = t >> 4;
        int c0 = (t & 15) * 8;
        if (r0 + row < n) {
            float4 v0 = *(const float4*)&s_x[row * 132 + c0];
            float4 v1 = *(const float4*)&s_x[row * 132 + c0 + 4];
            unsigned u0 = (unsigned)f2h(v0.x) | ((unsigned)f2h(v0.y) << 16);
            unsigned u1 = (unsigned)f2h(v0.z) | ((unsigned)f2h(v0.w) << 16);
            unsigned u2 = (unsigned)f2h(v1.x) | ((unsigned)f2h(v1.y) << 16);
            unsigned u3 = (unsigned)f2h(v1.z) | ((unsigned)f2h(v1.w) << 16);
            size_t off = (size_t)(r0 + row) * 128 + c0;
            *(uint4*)(xf + off) = make_uint4(u0, u1, u2, u3);
        }
    }
}

// ---------------------------------------------------------------------------
// Kernel 2: round-6 structure with ONE fix: s_rows row stride 128 -> 136 fp16
// (272 B). Round 6's 256B stride made the phase-C b128 stores hit only banks
// 0-15 (start bank 4q%32), 16 lanes deep -> 2.24e7 bank conflicts ~= 448
// extra cycles/wave ~= 30% of k2. With 272B stride start bank = 4(m+q)%32:
// all 32 banks covered evenly 8-deep = conflict-free minimum. G-phase read
// bank (4b + l)%32: 2 lanes/bank = free.
// ---------------------------------------------------------------------------
__global__ __launch_bounds__(64, 4) void k2_conv(
    const float* __restrict__ ew, const int* __restrict__ nbr,
    const float* __restrict__ bias, const unsigned short* __restrict__ xf,
    float* __restrict__ outp, int n) {
    __shared__ float s_w[52];
    __shared__ int s_nb[52];
    __shared__ float s_tw[32];
    __shared__ int s_id[32];
    __shared__ float s_diag[32];
    __shared__ float s_dist[32];
    __shared__ float s_omega[32];
    __shared__ _Float16 s_rows[32][136];  // 8.7 KB, padded stride (see above)

    int i = blockIdx.x;
    int l = threadIdx.x;

    // A: candidates = 48 neighbors + self loop (weight 1.0)
    if (l < DEG + 1) {
        bool self = (l == DEG);
        s_w[l] = self ? 1.0f : ew[(size_t)i * DEG + l];
        s_nb[l] = self ? i : nbr[(size_t)i * DEG + l];
    }
    __syncthreads();

    // B: rank-based top-k (exact jax.lax.top_k tie semantics); rank == slot
    if (l < DEG + 1) {
        float wj = s_w[l];
        int rank = 0;
#pragma unroll
        for (int t2 = 0; t2 < DEG + 1; ++t2) {
            float wt = s_w[t2];
            rank += (wt > wj) || ((wt == wj) && (t2 < l)) ? 1 : 0;
        }
        if (rank < TOPK) {
            s_tw[rank] = wj;
            s_id[rank] = s_nb[l];
        }
    }
    __syncthreads();

    // C: gather the 8 fragments ONCE, stage to LDS for the epilogue.
    int m = l & 15;
    int q = l >> 4;
    int row0 = s_id[m];
    int row1 = s_id[16 + m];
    const _Float16* g0 = (const _Float16*)xf + (size_t)row0 * 128 + q * 8;
    const _Float16* g1 = (const _Float16*)xf + (size_t)row1 * 128 + q * 8;

    halfx8 H0[4], H1[4];
#pragma unroll
    for (int kt = 0; kt < 4; ++kt) {
        H0[kt] = *(const halfx8*)(g0 + kt * 32);
        H1[kt] = *(const halfx8*)(g1 + kt * 32);
    }
#pragma unroll
    for (int kt = 0; kt < 4; ++kt) {
        *(halfx8*)&s_rows[m][kt * 32 + q * 8] = H0[kt];
        *(halfx8*)&s_rows[16 + m][kt * 32 + q * 8] = H1[kt];
    }

    // D: Gram = X*X^T directly in fp16 (fp32 accumulate)
    floatx4 acc[2][2];
#pragma unroll
    for (int a = 0; a < 2; ++a)
#pragma unroll
        for (int b = 0; b < 2; ++b) acc[a][b] = (floatx4){0.f, 0.f, 0.f, 0.f};

#pragma unroll
    for (int kt = 0; kt < 4; ++kt) {
        halfx8 h0 = H0[kt], h1 = H1[kt];
        acc[0][0] = __builtin_amdgcn_mfma_f32_16x16x32_f16(h0, h0, acc[0][0], 0, 0, 0);
        acc[0][1] = __builtin_amdgcn_mfma_f32_16x16x32_f16(h0, h1, acc[0][1], 0, 0, 0);
        acc[1][0] = __builtin_amdgcn_mfma_f32_16x16x32_f16(h1, h0, acc[1][0], 0, 0, 0);
        acc[1][1] = __builtin_amdgcn_mfma_f32_16x16x32_f16(h1, h1, acc[1][1], 0, 0, 0);
    }

    // D2: extract diagonal (sq) from Gram so that d2_aa == 0 exactly
    if (q == (m >> 2)) {
        int rd = m & 3;
        s_diag[m] = acc[0][0][rd];
        s_diag[16 + m] = acc[1][1][rd];
    }
    __syncthreads();

    // E: dist[a] = sum_b tw[b] * sqrt(d2 masked by d2>0)
    {
        float db0 = s_diag[m];
        float db1 = s_diag[16 + m];
        float tw0 = s_tw[m];
        float tw1 = s_tw[16 + m];
#pragma unroll
        for (int ma = 0; ma < 2; ++ma) {
#pragma unroll
            for (int r = 0; r < 4; ++r) {
                int a = ma * 16 + q * 4 + r;
                float da = s_diag[a];
                float g0v = acc[ma][0][r];
                float g1v = acc[ma][1][r];
                float d20 = da + db0 - 2.0f * g0v;
                float d21 = da + db1 - 2.0f * g1v;
                float t0 = (d20 > 0.0f) ? fast_sqrt(d20) : 0.0f;
                float t1 = (d21 > 0.0f) ? fast_sqrt(d21) : 0.0f;
                float v = tw0 * t0 + tw1 * t1;
                v += __shfl_xor(v, 1);
                v += __shfl_xor(v, 2);
                v += __shfl_xor(v, 4);
                v += __shfl_xor(v, 8);
                if (m == 0) s_dist[a] = v;
            }
        }
    }
    __syncthreads();

    // F: omega = exp(-dist - max(-dist)) * tw, normalized
    {
        int k32 = l & 31;
        float s = s_dist[k32];
        float mn = s;
        mn = fminf(mn, __shfl_xor(mn, 1));
        mn = fminf(mn, __shfl_xor(mn, 2));
        mn = fminf(mn, __shfl_xor(mn, 4));
        mn = fminf(mn, __shfl_xor(mn, 8));
        mn = fminf(mn, __shfl_xor(mn, 16));
        float e = fast_exp(mn - s) * s_tw[k32];
        float sum = e;
        sum += __shfl_xor(sum, 1);
        sum += __shfl_xor(sum, 2);
        sum += __shfl_xor(sum, 4);
        sum += __shfl_xor(sum, 8);
        sum += __shfl_xor(sum, 16);
        float om = e * fast_rcp(sum);
        if (l < 32) s_omega[l] = om;
    }
    __syncthreads();

    // G: aggregate from LDS — lane l owns output columns {2l, 2l+1}.
    {
        int d0 = 2 * l;
        float2 bb = *(const float2*)(bias + d0);
        float o0 = bb.x, o1 = bb.y;
#pragma unroll
        for (int b = 0; b < 32; ++b) {
            float wb = s_omega[b];
            unsigned uu = *(const unsigned*)&s_rows[b][d0];
            o0 += wb * h2f((unsigned short)(uu & 0xffff));
            o1 += wb * h2f((unsigned short)(uu >> 16));
        }
        *(float2*)(outp + (size_t)i * 128 + d0) = make_float2(o0, o1);
    }
}

extern "C" void kernel_launch(void* const* d_in, const int* in_sizes, int n_in,
                              void* d_out, int out_size, void* d_ws, size_t ws_size,
                              hipStream_t stream) {
    const float* feat = (const float*)d_in[0];
    const float* ew = (const float*)d_in[1];
    const float* weight = (const float*)d_in[2];
    const float* bias = (const float*)d_in[3];
    const int* nbr = (const int*)d_in[4];
    float* outp = (float*)d_out;
    int n = in_sizes[0] / NNODE_DIN;  // 50000

    unsigned short* xf = (unsigned short*)d_ws;            // n x 128 fp16
    unsigned short* wth = xf + (size_t)n * NNODE_DOUT;     // 2048 frags x 16B
    unsigned short* wtl = wth + 2048 * 8;

    hipLaunchKernelGGL(k0_wprep, dim3(8), dim3(256), 0, stream, weight, wth, wtl);
    int grid1 = (n + 15) / 16;
    hipLaunchKernelGGL(k1_mfma, dim3(grid1), dim3(256), 0, stream, feat, wth, wtl, xf, n);
    hipLaunchKernelGGL(k2_conv, dim3(n), dim3(64), 0, stream, ew, nbr, bias, xf, outp, n);
}

// Round 8
// 176.750 us; speedup vs baseline: 2.4830x; 1.0853x over previous
//
#include <hip/hip_runtime.h>
#include <hip/hip_bf16.h>

// Problem constants (match reference)
#define NNODE_DIN 128
#define NNODE_DOUT 128
#define DEG 48
#define TOPK 32

typedef _Float16 halfx8 __attribute__((ext_vector_type(8)));
typedef unsigned short ushortx8 __attribute__((ext_vector_type(8)));
typedef float floatx4 __attribute__((ext_vector_type(4)));

__device__ inline unsigned short f2h(float f) {
    _Float16 h = (_Float16)f;
    return __builtin_bit_cast(unsigned short, h);
}
__device__ inline float h2f(unsigned short u) {
    return (float)__builtin_bit_cast(_Float16, u);
}
// Raw transcendentals: proven correct in rounds 1-7 (absmax unchanged).
__device__ inline float fast_sqrt(float x) {
    float r; asm("v_sqrt_f32 %0, %1" : "=v"(r) : "v"(x)); return r;
}
__device__ inline float fast_exp(float x) {  // e^x, x <= 0 here (no overflow path)
    float t = x * 1.44269504088896341f;
    float r; asm("v_exp_f32 %0, %1" : "=v"(r) : "v"(t)); return r;
}
__device__ inline float fast_rcp(float x) {
    float r; asm("v_rcp_f32 %0, %1" : "=v"(r) : "v"(x)); return r;
}

// ---------------------------------------------------------------------------
// Kernel 0: pre-swizzle W^T into split-FP16 MFMA B-fragments in k1's load
// order. frag (nt,kt,lane) holds W[k][n], n = nt*16+(lane&15),
// k = kt*32+(lane>>4)*8+e. (unchanged)
// ---------------------------------------------------------------------------
__global__ __launch_bounds__(256) void k0_wprep(
    const float* __restrict__ w, unsigned short* __restrict__ wth,
    unsigned short* __restrict__ wtl) {
    int tid = blockIdx.x * 256 + threadIdx.x;  // 0..2047
    int lane = tid & 63;
    int kt = (tid >> 6) & 3;
    int nt = tid >> 8;
    int m = lane & 15, q = lane >> 4;
    int nn = nt * 16 + m;
    int k0 = kt * 32 + q * 8;
    ushortx8 uh, ul;
#pragma unroll
    for (int e = 0; e < 8; ++e) {
        float v = w[(size_t)(k0 + e) * 128 + nn];
        unsigned short h = f2h(v);
        uh[e] = h;
        ul[e] = f2h(v - h2f(h));
    }
    *(ushortx8*)(wth + tid * 8) = uh;
    *(ushortx8*)(wtl + tid * 8) = ul;
}

// ---------------------------------------------------------------------------
// Kernel 1: x = feat @ W via split-FP16 MFMA. REVERTED to the round-6 shape
// (single wave per 16-row block): the round-7 4-wave split REGRESSED the
// non-k2 residue 83.6 -> 96.5 us (duplicated A-prep + 4x redundant feat
// loads). Best measured configuration; frozen.
// ---------------------------------------------------------------------------
__global__ __launch_bounds__(64, 4) void k1_mfma(
    const float* __restrict__ feat, const unsigned short* __restrict__ wth,
    const unsigned short* __restrict__ wtl, unsigned short* __restrict__ xf,
    int n) {
    __shared__ float s_x[16 * 132];
    int l = threadIdx.x;
    int m = l & 15, q = l >> 4;
    int r0 = blockIdx.x * 16;

    halfx8 ah[4], al[4];
#pragma unroll
    for (int kt = 0; kt < 4; ++kt) {
        float vv[8];
        if (r0 + m < n) {
            const float* src = feat + (size_t)(r0 + m) * 128 + kt * 32 + q * 8;
            float4 v0 = *(const float4*)src;
            float4 v1 = *(const float4*)(src + 4);
            vv[0] = v0.x; vv[1] = v0.y; vv[2] = v0.z; vv[3] = v0.w;
            vv[4] = v1.x; vv[5] = v1.y; vv[6] = v1.z; vv[7] = v1.w;
        } else {
#pragma unroll
            for (int e = 0; e < 8; ++e) vv[e] = 0.0f;
        }
        ushortx8 uh, ul;
#pragma unroll
        for (int e = 0; e < 8; ++e) {
            unsigned short h = f2h(vv[e]);
            uh[e] = h;
            ul[e] = f2h(vv[e] - h2f(h));
        }
        ah[kt] = __builtin_bit_cast(halfx8, uh);
        al[kt] = __builtin_bit_cast(halfx8, ul);
    }

#pragma unroll 2
    for (int nt = 0; nt < 8; ++nt) {
        floatx4 a = (floatx4){0.f, 0.f, 0.f, 0.f};
#pragma unroll
        for (int kt = 0; kt < 4; ++kt) {
            int fo = ((nt * 4 + kt) * 64 + l) * 8;
            halfx8 bh = *(const halfx8*)(wth + fo);
            halfx8 bl = *(const halfx8*)(wtl + fo);
            a = __builtin_amdgcn_mfma_f32_16x16x32_f16(ah[kt], bh, a, 0, 0, 0);
            a = __builtin_amdgcn_mfma_f32_16x16x32_f16(ah[kt], bl, a, 0, 0, 0);
            a = __builtin_amdgcn_mfma_f32_16x16x32_f16(al[kt], bh, a, 0, 0, 0);
        }
#pragma unroll
        for (int r = 0; r < 4; ++r)
            s_x[(q * 4 + r) * 132 + nt * 16 + m] = a[r];
    }
    __syncthreads();

#pragma unroll
    for (int rr = 0; rr < 2; ++rr) {
        int row = rr * 8 + (l >> 3);
        int c0 = (l & 7) * 16;
        if (r0 + row < n) {
            float vv[16];
#pragma unroll
            for (int j = 0; j < 4; ++j) {
                float4 v = *(const float4*)&s_x[row * 132 + c0 + j * 4];
                vv[j * 4 + 0] = v.x; vv[j * 4 + 1] = v.y;
                vv[j * 4 + 2] = v.z; vv[j * 4 + 3] = v.w;
            }
            unsigned u[8];
#pragma unroll
            for (int p = 0; p < 8; ++p) {
                u[p] = (unsigned)f2h(vv[2 * p]) | ((unsigned)f2h(vv[2 * p + 1]) << 16);
            }
            size_t off = (size_t)(r0 + row) * 128 + c0;
            *(uint4*)(xf + off) = make_uint4(u[0], u[1], u[2], u[3]);
            *(uint4*)(xf + off + 8) = make_uint4(u[4], u[5], u[6], u[7]);
        }
    }
}

// ---------------------------------------------------------------------------
// Kernel 2: ROUND-8 RESTRUCTURE — one node per 128-thread block (2 waves).
// Rationale: k2 stuck gather-latency-bound at occ 40% (LDS 10.2 KB per NODE
// caps residency at ~15 single-wave WGs/CU; one wave serializes 8 gathers).
// Now wave w owns a-rows [16w,16w+16): 4 gather loads/lane (was 8), stages
// to the shared s_rows, reads the other wave's 16 rows from LDS (pattern
// measured conflict-free in r7), computes 2 Gram quadrants (8 MFMAs/wave).
// Per-wave LDS halves -> up to 32 waves/CU; per-node gather latency is split
// across 2 waves. All barriers uniform __syncthreads (proven). VGPR ~60 at
// (128,4), far from the spill regime (starts at cap 85).
// ---------------------------------------------------------------------------
__global__ __launch_bounds__(128, 4) void k2_conv(
    const float* __restrict__ ew, const int* __restrict__ nbr,
    const float* __restrict__ bias, const unsigned short* __restrict__ xf,
    float* __restrict__ outp, int n) {
    __shared__ float s_w[52];
    __shared__ int s_nb[52];
    __shared__ float s_tw[32];
    __shared__ int s_id[32];
    __shared__ float s_diag[32];
    __shared__ float s_dist[32];
    __shared__ float s_omega[32];
    __shared__ _Float16 s_rows[32][136];  // 8.7 KB, padded stride (r7-proven)

    int i = blockIdx.x;
    int t = threadIdx.x;
    int w = t >> 6;   // wave 0..1
    int l = t & 63;

    // A: candidates = 48 neighbors + self loop (threads 0..48)
    if (t < DEG + 1) {
        bool self = (t == DEG);
        s_w[t] = self ? 1.0f : ew[(size_t)i * DEG + t];
        s_nb[t] = self ? i : nbr[(size_t)i * DEG + t];
    }
    __syncthreads();

    // B: rank-based top-k (exact jax.lax.top_k tie semantics); rank == slot
    if (t < DEG + 1) {
        float wj = s_w[t];
        int rank = 0;
#pragma unroll
        for (int t2 = 0; t2 < DEG + 1; ++t2) {
            float wt = s_w[t2];
            rank += (wt > wj) || ((wt == wj) && (t2 < t)) ? 1 : 0;
        }
        if (rank < TOPK) {
            s_tw[rank] = wj;
            s_id[rank] = s_nb[t];
        }
    }
    __syncthreads();

    // C: wave w gathers its 16 rows (4 x dwordx4 per lane), stages to LDS.
    int m = l & 15;
    int q = l >> 4;
    int a0 = w * 16;       // own row base
    int o0 = 16 - a0;      // other wave's row base
    int rowg = s_id[a0 + m];
    const _Float16* gp = (const _Float16*)xf + (size_t)rowg * 128 + q * 8;

    halfx8 Hown[4];
#pragma unroll
    for (int kt = 0; kt < 4; ++kt) Hown[kt] = *(const halfx8*)(gp + kt * 32);
#pragma unroll
    for (int kt = 0; kt < 4; ++kt)
        *(halfx8*)&s_rows[a0 + m][kt * 32 + q * 8] = Hown[kt];
    __syncthreads();

    // D: Gram quadrants for own a-rows vs {own, other} b-rows.
    // mfma(A,B) with both frags in row-per-(lane&15) layout gives
    // D[row=q*4+r][col=m] = sum_k A[row][k]*B[col][k].
    halfx8 Hoth[4];
#pragma unroll
    for (int kt = 0; kt < 4; ++kt)
        Hoth[kt] = *(const halfx8*)&s_rows[o0 + m][kt * 32 + q * 8];

    floatx4 accO = (floatx4){0.f, 0.f, 0.f, 0.f};  // G[a0+i][a0+j]
    floatx4 accX = (floatx4){0.f, 0.f, 0.f, 0.f};  // G[a0+i][o0+j]
#pragma unroll
    for (int kt = 0; kt < 4; ++kt) {
        accO = __builtin_amdgcn_mfma_f32_16x16x32_f16(Hown[kt], Hown[kt], accO, 0, 0, 0);
        accX = __builtin_amdgcn_mfma_f32_16x16x32_f16(Hown[kt], Hoth[kt], accX, 0, 0, 0);
    }

    // D2: diagonal from own quadrant (row==col -> d2_aa == 0 exactly)
    if (q == (m >> 2)) {
        s_diag[a0 + m] = accO[m & 3];
    }
    __syncthreads();

    // E: dist[a] = sum over all 32 b of tw[b]*sqrt(d2>0 ? d2 : 0), a in own 16
    {
        float dbO = s_diag[a0 + m];
        float dbX = s_diag[o0 + m];
        float twO = s_tw[a0 + m];
        float twX = s_tw[o0 + m];
#pragma unroll
        for (int r = 0; r < 4; ++r) {
            int a = a0 + q * 4 + r;
            float da = s_diag[a];
            float d2o = da + dbO - 2.0f * accO[r];
            float d2x = da + dbX - 2.0f * accX[r];
            float t0 = (d2o > 0.0f) ? fast_sqrt(d2o) : 0.0f;
            float t1 = (d2x > 0.0f) ? fast_sqrt(d2x) : 0.0f;
            float v = twO * t0 + twX * t1;
            v += __shfl_xor(v, 1);
            v += __shfl_xor(v, 2);
            v += __shfl_xor(v, 4);
            v += __shfl_xor(v, 8);
            if (m == 0) s_dist[a] = v;
        }
    }
    __syncthreads();

    // F: omega = exp(-dist - max(-dist)) * tw, normalized (wave 0 computes)
    if (w == 0) {
        int k32 = l & 31;
        float s = s_dist[k32];
        float mn = s;
        mn = fminf(mn, __shfl_xor(mn, 1));
        mn = fminf(mn, __shfl_xor(mn, 2));
        mn = fminf(mn, __shfl_xor(mn, 4));
        mn = fminf(mn, __shfl_xor(mn, 8));
        mn = fminf(mn, __shfl_xor(mn, 16));
        float e = fast_exp(mn - s) * s_tw[k32];
        float sum = e;
        sum += __shfl_xor(sum, 1);
        sum += __shfl_xor(sum, 2);
        sum += __shfl_xor(sum, 4);
        sum += __shfl_xor(sum, 8);
        sum += __shfl_xor(sum, 16);
        float om = e * fast_rcp(sum);
        if (l < 32) s_omega[l] = om;
    }
    __syncthreads();

    // G: thread t owns output column t; read s_rows[b][t] (2 lanes/bank =
    // free) with broadcast s_omega[b]. One coalesced float store per thread.
    {
        float o = bias[t];
#pragma unroll
        for (int b = 0; b < 32; ++b) {
            o += s_omega[b] * (float)s_rows[b][t];
        }
        outp[(size_t)i * 128 + t] = o;
    }
}

extern "C" void kernel_launch(void* const* d_in, const int* in_sizes, int n_in,
                              void* d_out, int out_size, void* d_ws, size_t ws_size,
                              hipStream_t stream) {
    const float* feat = (const float*)d_in[0];
    const float* ew = (const float*)d_in[1];
    const float* weight = (const float*)d_in[2];
    const float* bias = (const float*)d_in[3];
    const int* nbr = (const int*)d_in[4];
    float* outp = (float*)d_out;
    int n = in_sizes[0] / NNODE_DIN;  // 50000

    unsigned short* xf = (unsigned short*)d_ws;            // n x 128 fp16
    unsigned short* wth = xf + (size_t)n * NNODE_DOUT;     // 2048 frags x 16B
    unsigned short* wtl = wth + 2048 * 8;

    hipLaunchKernelGGL(k0_wprep, dim3(8), dim3(256), 0, stream, weight, wth, wtl);
    int grid1 = (n + 15) / 16;
    hipLaunchKernelGGL(k1_mfma, dim3(grid1), dim3(64), 0, stream, feat, wth, wtl, xf, n);
    hipLaunchKernelGGL(k2_conv, dim3(n), dim3(128), 0, stream, ew, nbr, bias, xf, outp, n);
}